// Round 14
// baseline (263.805 us; speedup 1.0000x reference)
//
#include <hip/hip_runtime.h>
#include <hip/hip_bf16.h>
#include <stdint.h>

typedef __attribute__((ext_vector_type(4))) float f32x4;
typedef __attribute__((ext_vector_type(16))) float f32x16;
typedef __attribute__((ext_vector_type(8))) short s16x8;
typedef __attribute__((ext_vector_type(4))) short s16x4;
typedef uint16_t u16;

#define DEV __device__ __forceinline__

static DEV u16 f2bf(float f) {
  union { float f; uint32_t u; } v; v.f = f;
  uint32_t r = v.u + 0x7fffu + ((v.u >> 16) & 1u);
  return (u16)(r >> 16);
}

static DEV uint32_t cvt_pk_bf16(float lo, float hi) {
  uint32_t r;
  asm("v_cvt_pk_bf16_f32 %0, %1, %2" : "=v"(r) : "v"(lo), "v"(hi));
  return r;
}

#define GLD_LDS16(gp, lp) __builtin_amdgcn_global_load_lds( \
    (const __attribute__((address_space(1))) void*)(gp),    \
    (__attribute__((address_space(3))) void*)(lp), 16, 0, 0)

// ---------------- Kernel 1: LayerNorm + pos_embed -> bf16 ----------------
__global__ __launch_bounds__(256) void k_ln(
    const float* __restrict__ x, const float* __restrict__ pos,
    const float* __restrict__ g, const float* __restrict__ be,
    u16* __restrict__ xp) {
  int row = blockIdx.x;
  size_t base = (size_t)row * 768;
  int t = threadIdx.x;
  float v0 = x[base + t], v1 = x[base + t + 256], v2 = x[base + t + 512];
  float s = v0 + v1 + v2;
  float ss = v0 * v0 + v1 * v1 + v2 * v2;
#pragma unroll
  for (int off = 1; off < 64; off <<= 1) {
    s += __shfl_xor(s, off);
    ss += __shfl_xor(ss, off);
  }
  __shared__ float red[8];
  int wave = t >> 6, lane = t & 63;
  if (lane == 0) { red[wave] = s; red[4 + wave] = ss; }
  __syncthreads();
  float tot = red[0] + red[1] + red[2] + red[3];
  float tss = red[4] + red[5] + red[6] + red[7];
  float mu = tot * (1.0f / 768.0f);
  float var = tss * (1.0f / 768.0f) - mu * mu;
  float rs = rsqrtf(var + 1e-5f);
  float vv[3] = {v0, v1, v2};
#pragma unroll
  for (int i = 0; i < 3; ++i) {
    int c = t + i * 256;
    float val = (vv[i] - mu) * rs * g[c] + be[c] + pos[base + c];
    xp[base + c] = f2bf(val);
  }
}

// ---------------- Kernel 2: transpose + cast f32[K][N] -> bf16[N][K] -----
__global__ __launch_bounds__(256) void k_tr(
    const float* __restrict__ in, u16* __restrict__ out, int K, int N) {
  __shared__ float tile[32][33];
  int n0 = blockIdx.x * 32, k0 = blockIdx.y * 32;
  int tx = threadIdx.x & 31, ty = threadIdx.x >> 5;
#pragma unroll
  for (int r = ty; r < 32; r += 8)
    tile[r][tx] = in[(size_t)(k0 + r) * N + n0 + tx];
  __syncthreads();
#pragma unroll
  for (int r = ty; r < 32; r += 8)
    out[(size_t)(n0 + r) * K + k0 + tx] = f2bf(tile[tx][r]);
}

// ---------------- Kernel 3: QKV GEMM  [8192,768] x [768,2304] ------------
// Q,K -> qkv [which][B,H,K,D]; V -> vtg [B,H,D,K] (fused transpose).
// Q is PRE-SCALED by 0.125*log2(e) so attention's exp2 arg needs no fma.
__global__ __launch_bounds__(256) void k_gemm_qkv(
    const u16* __restrict__ A, const u16* __restrict__ Bt,
    const float* __restrict__ bias, u16* __restrict__ qkv,
    u16* __restrict__ vtg) {
  __shared__ u16 Al[128 * 64];
  __shared__ u16 Bl[128 * 64];
  const size_t BHKD = (size_t)48 * 2048 * 64;
  int mt = blockIdx.x, nt = blockIdx.y;
  int t = threadIdx.x, wave = t >> 6, lane = t & 63;
  int lr = lane & 15, lg = lane >> 4;
  f32x4 acc[4][4];
#pragma unroll
  for (int i = 0; i < 4; ++i)
#pragma unroll
    for (int j = 0; j < 4; ++j) acc[i][j] = (f32x4){0.f, 0.f, 0.f, 0.f};
  const size_t Ab = (size_t)mt * 128 * 768;
  const size_t Bb = (size_t)nt * 128 * 768;
  int wr = (wave >> 1) * 64, wc = (wave & 1) * 64;
  for (int kt = 0; kt < 12; ++kt) {
#pragma unroll
    for (int c = 0; c < 4; ++c) {
      int q = c * 256 + t;
      int row = q >> 3, ch = q & 7;
      int sc = ch ^ (row & 7);
      GLD_LDS16(A + Ab + (size_t)row * 768 + kt * 64 + sc * 8,
                &Al[(size_t)(c * 256 + wave * 64) * 8]);
      GLD_LDS16(Bt + Bb + (size_t)row * 768 + kt * 64 + sc * 8,
                &Bl[(size_t)(c * 256 + wave * 64) * 8]);
    }
    __syncthreads();
#pragma unroll
    for (int ki = 0; ki < 2; ++ki) {
      s16x8 af[4], bf[4];
#pragma unroll
      for (int mi = 0; mi < 4; ++mi)
        af[mi] = *(const s16x8*)&Al[(wr + mi * 16 + lr) * 64 +
                                    (((ki * 4 + lg) ^ (lr & 7)) * 8)];
#pragma unroll
      for (int ni = 0; ni < 4; ++ni)
        bf[ni] = *(const s16x8*)&Bl[(wc + ni * 16 + lr) * 64 +
                                    (((ki * 4 + lg) ^ (lr & 7)) * 8)];
#pragma unroll
      for (int mi = 0; mi < 4; ++mi)
#pragma unroll
        for (int ni = 0; ni < 4; ++ni)
          acc[mi][ni] = __builtin_amdgcn_mfma_f32_16x16x32_bf16(
              af[mi], bf[ni], acc[mi][ni], 0, 0, 0);
    }
    __syncthreads();
  }
  int which0 = (nt * 128) / 768;           // block-uniform (768 = 6*128)
  float qscale = (which0 == 0) ? 0.1803368801f : 1.0f;
#pragma unroll
  for (int ni = 0; ni < 4; ++ni) {
    int col = wc + ni * 16 + lr;
    int n = nt * 128 + col;
    int which = n / 768, cc = n % 768;
    int h = cc >> 6, d = cc & 63;
    float bs = bias[n];
    if (which == 2) {
#pragma unroll
      for (int mi = 0; mi < 4; ++mi) {
        int m0 = mt * 128 + wr + mi * 16 + lg * 4;
        int b = m0 >> 11, kp0 = m0 & 2047;
        s16x4 o4;
#pragma unroll
        for (int j = 0; j < 4; ++j) o4[j] = (short)f2bf(acc[mi][ni][j] + bs);
        *(s16x4*)&vtg[((size_t)(b * 12 + h) * 64 + d) * 2048 + kp0] = o4;
      }
    } else {
#pragma unroll
      for (int mi = 0; mi < 4; ++mi) {
#pragma unroll
        for (int j = 0; j < 4; ++j) {
          int row = wr + mi * 16 + lg * 4 + j;
          int m = mt * 128 + row;
          int b = m >> 11, kp = m & 2047;
          size_t dst = (size_t)which * BHKD +
                       (((size_t)b * 12 + h) * 2048 + kp) * 64 + d;
          qkv[dst] = f2bf((acc[mi][ni][j] + bs) * qscale);
        }
      }
    }
  }
}

// ---------------- Kernel 4: flash attention (cross-tile pipelined) -------
// Per phase: stage(t+2) | QK of tile t+1 (from LDS, already resident)
// overlapped with exp/cvt/PV of tile t (sa carried in registers from the
// previous phase). Two independent chains -> compiler interleaves MFMA/VALU.
// sa carried in two named register sets (saA/saB), 2-phase unrolled loop.
#define STAGE_KV(KB, VB, ktt) do {                                          \
  _Pragma("unroll")                                                         \
  for (int c_ = 0; c_ < 2; ++c_) {                                          \
    int q_ = c_ * 256 + t; int r_ = q_ >> 3, ch_ = q_ & 7;                  \
    int sc_ = ch_ ^ (r_ & 7);                                               \
    int gk_ = (r_ & 0x33) | ((r_ & 4) << 1) | ((r_ & 8) >> 1);              \
    GLD_LDS16(Kg + ((size_t)((ktt) * 64 + gk_)) * 64 + sc_ * 8,             \
              &KB[(c_ * 256 + wave * 64) * 8]);                             \
    GLD_LDS16(Vt + (size_t)r_ * 2048 + (ktt) * 64 + sc_ * 8,                \
              &VB[(c_ * 256 + wave * 64) * 8]);                             \
  }                                                                         \
} while (0)

#define LOAD_B(BR, ktt) do {                                                \
  _Pragma("unroll")                                                         \
  for (int kv_ = 0; kv_ < 2; ++kv_) {                                       \
    _Pragma("unroll")                                                       \
    for (int rn_ = 0; rn_ < 2; ++rn_) {                                     \
      const float* bp_ = Bgl + (ktt) * 64 + kv_ * 32 + rn_ * 16;            \
      BR[(kv_ * 2 + rn_) * 2]     = *(const f32x4*)bp_;                     \
      BR[(kv_ * 2 + rn_) * 2 + 1] = *(const f32x4*)(bp_ + 4);               \
    }                                                                       \
  }                                                                         \
} while (0)

#define QK_PART(SN, KB, BV) do {                                            \
  _Pragma("unroll")                                                         \
  for (int kv_ = 0; kv_ < 2; ++kv_)                                         \
    _Pragma("unroll")                                                       \
    for (int r = 0; r < 16; ++r)                                            \
      SN[kv_][r] = 1.4426950409f *                                          \
          BV[kv_ * 4 + (r >> 3) * 2 + ((r >> 2) & 1)][r & 3];               \
  _Pragma("unroll")                                                         \
  for (int ki = 0; ki < 4; ++ki) {                                          \
    _Pragma("unroll")                                                       \
    for (int kv_ = 0; kv_ < 2; ++kv_) {                                     \
      s16x8 kf = *(const s16x8*)&KB[(kv_ * 32 + l31) * 64 +                 \
                                    (((ki * 2 + hi) ^ (l31 & 7)) * 8)];     \
      SN[kv_] = __builtin_amdgcn_mfma_f32_32x32x16_bf16(kf, qf[ki],         \
                                                        SN[kv_], 0, 0, 0);  \
    }                                                                       \
  }                                                                         \
} while (0)

#define PV_PART(SP, VB) do {                                                \
  float p_[32];                                                             \
  _Pragma("unroll")                                                         \
  for (int kv_ = 0; kv_ < 2; ++kv_)                                         \
    _Pragma("unroll")                                                       \
    for (int r = 0; r < 16; ++r)                                            \
      p_[kv_ * 16 + r] = exp2f(SP[kv_][r]);                                 \
  union { uint32_t u[4]; s16x8 v; } pa_[4];                                 \
  _Pragma("unroll")                                                         \
  for (int s = 0; s < 4; ++s)                                               \
    _Pragma("unroll")                                                       \
    for (int w = 0; w < 4; ++w)                                             \
      pa_[s].u[w] = cvt_pk_bf16(p_[(s >> 1) * 16 + (s & 1) * 8 + 2 * w],    \
                                p_[(s >> 1) * 16 + (s & 1) * 8 + 2 * w + 1]);\
  _Pragma("unroll")                                                         \
  for (int s = 0; s < 4; ++s) {                                             \
    lacc = __builtin_amdgcn_mfma_f32_32x32x16_bf16(onesv, pa_[s].v,         \
                                                   lacc, 0, 0, 0);          \
    _Pragma("unroll")                                                       \
    for (int dt = 0; dt < 2; ++dt) {                                        \
      s16x8 vf = *(const s16x8*)&VB[(dt * 32 + l31) * 64 +                  \
                                    (((s * 2 + hi) ^ (l31 & 7)) * 8)];      \
      oacc[dt] = __builtin_amdgcn_mfma_f32_32x32x16_bf16(vf, pa_[s].v,      \
                                                         oacc[dt], 0, 0, 0);\
    }                                                                       \
  }                                                                         \
} while (0)

// phase for tile ktt: PV(ktt) from buf B0 using SP; QK(ktt+1) from buf B1
// into SN; stage ktt+2 into buf B2.
#define PHASE(ktt, SP, SN, B0, B1, B2, DOSTAGE, DOQK) do {                  \
  f32x4 bv_[8];                                                             \
  if (DOQK) LOAD_B(bv_, (ktt) + 1);                                         \
  if (DOSTAGE) STAGE_KV(Kl[B2], Vl[B2], (ktt) + 2);                         \
  if (DOQK) QK_PART(SN, Kl[B1], bv_);                                       \
  PV_PART(SP, Vl[B0]);                                                      \
  __syncthreads();                                                          \
} while (0)

__global__ __launch_bounds__(256, 3) void k_attn(
    const u16* __restrict__ qkv, const u16* __restrict__ vtg,
    const float* __restrict__ bias, u16* __restrict__ ctx) {
  __shared__ u16 Kl[3][64 * 64];
  __shared__ u16 Vl[3][64 * 64];
  int bid = blockIdx.x;
  int swz = (bid & 7) * 96 + (bid >> 3);   // 768 = 8*96, bijective
  int h = swz % 12;
  int bq = swz / 12;        // 0..63
  int qt = bq & 15;
  int b = bq >> 4;
  int bh = b * 12 + h;
  int t = threadIdx.x, wave = t >> 6, lane = t & 63;
  int l31 = lane & 31, hi = lane >> 5;
  const size_t BHKD = (size_t)48 * 2048 * 64;
  const u16* Q = qkv + (size_t)bh * 2048 * 64;
  const u16* Kg = Q + BHKD;
  const u16* Vt = vtg + (size_t)bh * 64 * 2048;
  int qrow = qt * 128 + wave * 32 + l31;
  const float* Bgl = bias + ((size_t)b * 2048 + qrow) * 2048 + hi * 8;
  s16x8 qf[4];
#pragma unroll
  for (int ki = 0; ki < 4; ++ki)
    qf[ki] = *(const s16x8*)&Q[(size_t)qrow * 64 + ki * 16 + hi * 8];
  s16x8 onesv;
#pragma unroll
  for (int i = 0; i < 8; ++i) onesv[i] = (short)0x3F80;   // bf16 1.0
  f32x16 oacc[2], lacc;
#pragma unroll
  for (int r = 0; r < 16; ++r) { oacc[0][r] = 0.f; oacc[1][r] = 0.f; lacc[r] = 0.f; }
  f32x16 saA[2], saB[2];

  // prologue: stage tiles 0,1; bias(0); full drain; QK(0) -> saA
  STAGE_KV(Kl[0], Vl[0], 0);
  STAGE_KV(Kl[1], Vl[1], 1);
  {
    f32x4 bv0[8];
    LOAD_B(bv0, 0);
    __syncthreads();
    QK_PART(saA, Kl[0], bv0);
  }
  int c0 = 0, c1 = 1, c2 = 2;
#pragma unroll 1
  for (int kt = 0; kt < 30; kt += 2) {
    PHASE(kt,     saA, saB, c0, c1, c2, 1, 1);
    PHASE(kt + 1, saB, saA, c1, c2, c0, 1, 1);
    int tmp = c2; c2 = c1; c1 = c0; c0 = tmp;   // (c0,c1,c2) = (c2,c0,c1)
  }
  PHASE(30, saA, saB, c0, c1, c2, 0, 1);
  PHASE(31, saB, saA, c1, c2, c0, 0, 0);

  float inv = 1.0f / lacc[0];
  size_t obase = ((size_t)b * 2048 + qrow) * 768 + h * 64;
#pragma unroll
  for (int dt = 0; dt < 2; ++dt) {
#pragma unroll
    for (int g = 0; g < 4; ++g) {
      s16x4 o4;
#pragma unroll
      for (int j = 0; j < 4; ++j)
        o4[j] = (short)f2bf(oacc[dt][g * 4 + j] * inv);
      *(s16x4*)&ctx[obase + dt * 32 + g * 8 + hi * 4] = o4;
    }
  }
}

// ---------------- Kernel 5: proj GEMM [8192,768] x [768,768] + b ---------
__global__ __launch_bounds__(256) void k_gemm_proj(
    const u16* __restrict__ A, const u16* __restrict__ Bt,
    const float* __restrict__ bias, float* __restrict__ out) {
  __shared__ u16 Al[128 * 64];
  __shared__ u16 Bl[128 * 64];
  int mt = blockIdx.x, nt = blockIdx.y;
  int t = threadIdx.x, wave = t >> 6, lane = t & 63;
  int lr = lane & 15, lg = lane >> 4;
  f32x4 acc[4][4];
#pragma unroll
  for (int i = 0; i < 4; ++i)
#pragma unroll
    for (int j = 0; j < 4; ++j) acc[i][j] = (f32x4){0.f, 0.f, 0.f, 0.f};
  const size_t Ab = (size_t)mt * 128 * 768;
  const size_t Bb = (size_t)nt * 128 * 768;
  int wr = (wave >> 1) * 64, wc = (wave & 1) * 64;
  for (int kt = 0; kt < 12; ++kt) {
#pragma unroll
    for (int c = 0; c < 4; ++c) {
      int q = c * 256 + t;
      int row = q >> 3, ch = q & 7;
      int sc = ch ^ (row & 7);
      GLD_LDS16(A + Ab + (size_t)row * 768 + kt * 64 + sc * 8,
                &Al[(size_t)(c * 256 + wave * 64) * 8]);
      GLD_LDS16(Bt + Bb + (size_t)row * 768 + kt * 64 + sc * 8,
                &Bl[(size_t)(c * 256 + wave * 64) * 8]);
    }
    __syncthreads();
#pragma unroll
    for (int ki = 0; ki < 2; ++ki) {
      s16x8 af[4], bf[4];
#pragma unroll
      for (int mi = 0; mi < 4; ++mi)
        af[mi] = *(const s16x8*)&Al[(wr + mi * 16 + lr) * 64 +
                                    (((ki * 4 + lg) ^ (lr & 7)) * 8)];
#pragma unroll
      for (int ni = 0; ni < 4; ++ni)
        bf[ni] = *(const s16x8*)&Bl[(wc + ni * 16 + lr) * 64 +
                                    (((ki * 4 + lg) ^ (lr & 7)) * 8)];
#pragma unroll
      for (int mi = 0; mi < 4; ++mi)
#pragma unroll
        for (int ni = 0; ni < 4; ++ni)
          acc[mi][ni] = __builtin_amdgcn_mfma_f32_16x16x32_bf16(
              af[mi], bf[ni], acc[mi][ni], 0, 0, 0);
    }
    __syncthreads();
  }
#pragma unroll
  for (int ni = 0; ni < 4; ++ni) {
    int col = wc + ni * 16 + lr;
    int n = nt * 128 + col;
    float bs = bias[n];
#pragma unroll
    for (int mi = 0; mi < 4; ++mi) {
#pragma unroll
      for (int j = 0; j < 4; ++j) {
        int row = wr + mi * 16 + lg * 4 + j;
        out[(size_t)(mt * 128 + row) * 768 + n] = acc[mi][ni][j] + bs;
      }
    }
  }
}

extern "C" void kernel_launch(void* const* d_in, const int* in_sizes, int n_in,
                              void* d_out, int out_size, void* d_ws, size_t ws_size,
                              hipStream_t stream) {
  const float* x      = (const float*)d_in[0];
  const float* pos    = (const float*)d_in[1];
  const float* bias   = (const float*)d_in[2];
  const float* ln_g   = (const float*)d_in[3];
  const float* ln_b   = (const float*)d_in[4];
  const float* qkv_w  = (const float*)d_in[5];
  const float* qkv_b  = (const float*)d_in[6];
  const float* proj_w = (const float*)d_in[7];
  const float* proj_b = (const float*)d_in[8];
  float* out = (float*)d_out;

  char* ws = (char*)d_ws;
  u16* xp      = (u16*)ws;              ws += 12582912;   // [8192][768]
  u16* qkv_wt  = (u16*)ws;              ws += 3538944;    // [2304][768]
  u16* proj_wt = (u16*)ws;              ws += 1179648;    // [768][768]
  u16* qkvbuf  = (u16*)ws;              ws += 25165824;   // Q,K [B,H,K,D]
  u16* ctx     = (u16*)ws;              ws += 12582912;   // [8192][768]
  u16* vtg     = (u16*)ws;              ws += 12582912;   // [B,H,D,K]

  k_ln<<<8192, 256, 0, stream>>>(x, pos, ln_g, ln_b, xp);
  k_tr<<<dim3(72, 24), 256, 0, stream>>>(qkv_w, qkv_wt, 768, 2304);
  k_tr<<<dim3(24, 24), 256, 0, stream>>>(proj_w, proj_wt, 768, 768);
  k_gemm_qkv<<<dim3(64, 18), 256, 0, stream>>>(xp, qkv_wt, qkv_b, qkvbuf, vtg);
  k_attn<<<768, 256, 0, stream>>>(qkvbuf, vtg, bias, ctx);
  k_gemm_proj<<<dim3(64, 6), 256, 0, stream>>>(ctx, proj_wt, proj_b, out);
}

// Round 15
// 200.835 us; speedup vs baseline: 1.3135x; 1.3135x over previous
//
#include <hip/hip_runtime.h>
#include <hip/hip_bf16.h>
#include <stdint.h>

typedef __attribute__((ext_vector_type(4))) float f32x4;
typedef __attribute__((ext_vector_type(16))) float f32x16;
typedef __attribute__((ext_vector_type(8))) short s16x8;
typedef __attribute__((ext_vector_type(4))) short s16x4;
typedef uint16_t u16;

#define DEV __device__ __forceinline__

static DEV u16 f2bf(float f) {
  union { float f; uint32_t u; } v; v.f = f;
  uint32_t r = v.u + 0x7fffu + ((v.u >> 16) & 1u);
  return (u16)(r >> 16);
}

static DEV float bf2f(u16 x) {
  union { uint32_t u; float f; } v; v.u = ((uint32_t)x) << 16;
  return v.f;
}

static DEV uint32_t cvt_pk_bf16(float lo, float hi) {
  uint32_t r;
  asm("v_cvt_pk_bf16_f32 %0, %1, %2" : "=v"(r) : "v"(lo), "v"(hi));
  return r;
}

#define GLD_LDS16(gp, lp) __builtin_amdgcn_global_load_lds( \
    (const __attribute__((address_space(1))) void*)(gp),    \
    (__attribute__((address_space(3))) void*)(lp), 16, 0, 0)

// ---------------- Kernel 0: bias f32 -> bf16 * log2(e) -------------------
__global__ __launch_bounds__(256) void k_bcast(
    const float* __restrict__ in, u16* __restrict__ out) {
  size_t i = ((size_t)blockIdx.x * 256 + threadIdx.x) * 8;
  f32x4 a = *(const f32x4*)(in + i);
  f32x4 b = *(const f32x4*)(in + i + 4);
  s16x8 o;
#pragma unroll
  for (int j = 0; j < 4; ++j) o[j] = (short)f2bf(a[j] * 1.4426950409f);
#pragma unroll
  for (int j = 0; j < 4; ++j) o[4 + j] = (short)f2bf(b[j] * 1.4426950409f);
  *(s16x8*)(out + i) = o;
}

// ---------------- Kernel 1: LayerNorm + pos_embed -> bf16 ----------------
__global__ __launch_bounds__(256) void k_ln(
    const float* __restrict__ x, const float* __restrict__ pos,
    const float* __restrict__ g, const float* __restrict__ be,
    u16* __restrict__ xp) {
  int row = blockIdx.x;
  size_t base = (size_t)row * 768;
  int t = threadIdx.x;
  float v0 = x[base + t], v1 = x[base + t + 256], v2 = x[base + t + 512];
  float s = v0 + v1 + v2;
  float ss = v0 * v0 + v1 * v1 + v2 * v2;
#pragma unroll
  for (int off = 1; off < 64; off <<= 1) {
    s += __shfl_xor(s, off);
    ss += __shfl_xor(ss, off);
  }
  __shared__ float red[8];
  int wave = t >> 6, lane = t & 63;
  if (lane == 0) { red[wave] = s; red[4 + wave] = ss; }
  __syncthreads();
  float tot = red[0] + red[1] + red[2] + red[3];
  float tss = red[4] + red[5] + red[6] + red[7];
  float mu = tot * (1.0f / 768.0f);
  float var = tss * (1.0f / 768.0f) - mu * mu;
  float rs = rsqrtf(var + 1e-5f);
  float vv[3] = {v0, v1, v2};
#pragma unroll
  for (int i = 0; i < 3; ++i) {
    int c = t + i * 256;
    float val = (vv[i] - mu) * rs * g[c] + be[c] + pos[base + c];
    xp[base + c] = f2bf(val);
  }
}

// ---------------- Kernel 2: transpose + cast f32[K][N] -> bf16[N][K] -----
__global__ __launch_bounds__(256) void k_tr(
    const float* __restrict__ in, u16* __restrict__ out, int K, int N) {
  __shared__ float tile[32][33];
  int n0 = blockIdx.x * 32, k0 = blockIdx.y * 32;
  int tx = threadIdx.x & 31, ty = threadIdx.x >> 5;
#pragma unroll
  for (int r = ty; r < 32; r += 8)
    tile[r][tx] = in[(size_t)(k0 + r) * N + n0 + tx];
  __syncthreads();
#pragma unroll
  for (int r = ty; r < 32; r += 8)
    out[(size_t)(n0 + r) * K + k0 + tx] = f2bf(tile[tx][r]);
}

// ---------------- Kernel 3: QKV GEMM  [8192,768] x [768,2304] ------------
// Q,K -> qkv [which][B,H,K,D]; V -> vtg [B,H,D,K] (fused transpose).
// Q is PRE-SCALED by 0.125*log2(e) so attention's exp2 arg needs no fma.
__global__ __launch_bounds__(256) void k_gemm_qkv(
    const u16* __restrict__ A, const u16* __restrict__ Bt,
    const float* __restrict__ bias, u16* __restrict__ qkv,
    u16* __restrict__ vtg) {
  __shared__ u16 Al[128 * 64];
  __shared__ u16 Bl[128 * 64];
  const size_t BHKD = (size_t)48 * 2048 * 64;
  int mt = blockIdx.x, nt = blockIdx.y;
  int t = threadIdx.x, wave = t >> 6, lane = t & 63;
  int lr = lane & 15, lg = lane >> 4;
  f32x4 acc[4][4];
#pragma unroll
  for (int i = 0; i < 4; ++i)
#pragma unroll
    for (int j = 0; j < 4; ++j) acc[i][j] = (f32x4){0.f, 0.f, 0.f, 0.f};
  const size_t Ab = (size_t)mt * 128 * 768;
  const size_t Bb = (size_t)nt * 128 * 768;
  int wr = (wave >> 1) * 64, wc = (wave & 1) * 64;
  for (int kt = 0; kt < 12; ++kt) {
#pragma unroll
    for (int c = 0; c < 4; ++c) {
      int q = c * 256 + t;
      int row = q >> 3, ch = q & 7;
      int sc = ch ^ (row & 7);
      GLD_LDS16(A + Ab + (size_t)row * 768 + kt * 64 + sc * 8,
                &Al[(size_t)(c * 256 + wave * 64) * 8]);
      GLD_LDS16(Bt + Bb + (size_t)row * 768 + kt * 64 + sc * 8,
                &Bl[(size_t)(c * 256 + wave * 64) * 8]);
    }
    __syncthreads();
#pragma unroll
    for (int ki = 0; ki < 2; ++ki) {
      s16x8 af[4], bf[4];
#pragma unroll
      for (int mi = 0; mi < 4; ++mi)
        af[mi] = *(const s16x8*)&Al[(wr + mi * 16 + lr) * 64 +
                                    (((ki * 4 + lg) ^ (lr & 7)) * 8)];
#pragma unroll
      for (int ni = 0; ni < 4; ++ni)
        bf[ni] = *(const s16x8*)&Bl[(wc + ni * 16 + lr) * 64 +
                                    (((ki * 4 + lg) ^ (lr & 7)) * 8)];
#pragma unroll
      for (int mi = 0; mi < 4; ++mi)
#pragma unroll
        for (int ni = 0; ni < 4; ++ni)
          acc[mi][ni] = __builtin_amdgcn_mfma_f32_16x16x32_bf16(
              af[mi], bf[ni], acc[mi][ni], 0, 0, 0);
    }
    __syncthreads();
  }
  int which0 = (nt * 128) / 768;           // block-uniform (768 = 6*128)
  float qscale = (which0 == 0) ? 0.1803368801f : 1.0f;
#pragma unroll
  for (int ni = 0; ni < 4; ++ni) {
    int col = wc + ni * 16 + lr;
    int n = nt * 128 + col;
    int which = n / 768, cc = n % 768;
    int h = cc >> 6, d = cc & 63;
    float bs = bias[n];
    if (which == 2) {
#pragma unroll
      for (int mi = 0; mi < 4; ++mi) {
        int m0 = mt * 128 + wr + mi * 16 + lg * 4;
        int b = m0 >> 11, kp0 = m0 & 2047;
        s16x4 o4;
#pragma unroll
        for (int j = 0; j < 4; ++j) o4[j] = (short)f2bf(acc[mi][ni][j] + bs);
        *(s16x4*)&vtg[((size_t)(b * 12 + h) * 64 + d) * 2048 + kp0] = o4;
      }
    } else {
#pragma unroll
      for (int mi = 0; mi < 4; ++mi) {
#pragma unroll
        for (int j = 0; j < 4; ++j) {
          int row = wr + mi * 16 + lg * 4 + j;
          int m = mt * 128 + row;
          int b = m >> 11, kp = m & 2047;
          size_t dst = (size_t)which * BHKD +
                       (((size_t)b * 12 + h) * 2048 + kp) * 64 + d;
          qkv[dst] = f2bf((acc[mi][ni][j] + bs) * qscale);
        }
      }
    }
  }
}

// ---------------- Kernel 4: flash attention (bf16 bias, slim) ------------
// R12 3-buf counted-vmcnt pipeline. Bias is pre-scaled bf16 (half the cache
// traffic of the dominant re-read stream); sa C-init = bf16->f32 shift;
// Q pre-scaled -> p = exp2(sa) bare. setprio(1) around MFMA clusters (T5).
#define STAGE_KV(KB, VB, ktt) do {                                          \
  _Pragma("unroll")                                                         \
  for (int c_ = 0; c_ < 2; ++c_) {                                          \
    int q_ = c_ * 256 + t; int r_ = q_ >> 3, ch_ = q_ & 7;                  \
    int sc_ = ch_ ^ (r_ & 7);                                               \
    int gk_ = (r_ & 0x33) | ((r_ & 4) << 1) | ((r_ & 8) >> 1);              \
    GLD_LDS16(Kg + ((size_t)((ktt) * 64 + gk_)) * 64 + sc_ * 8,             \
              &KB[(c_ * 256 + wave * 64) * 8]);                             \
    GLD_LDS16(Vt + (size_t)r_ * 2048 + (ktt) * 64 + sc_ * 8,                \
              &VB[(c_ * 256 + wave * 64) * 8]);                             \
  }                                                                         \
} while (0)

#define LOAD_B(BR, ktt) do {                                                \
  const u16* bp_ = Bgl + (ktt) * 64;                                        \
  BR[0] = *(const s16x8*)(bp_);                                             \
  BR[1] = *(const s16x8*)(bp_ + 16);                                        \
  BR[2] = *(const s16x8*)(bp_ + 32);                                        \
  BR[3] = *(const s16x8*)(bp_ + 48);                                        \
} while (0)

#define COMPUTE_TILE(KB, VB, BV) do {                                       \
  f32x16 sa_[2];                                                            \
  _Pragma("unroll")                                                         \
  for (int kv_ = 0; kv_ < 2; ++kv_)                                         \
    _Pragma("unroll")                                                       \
    for (int r = 0; r < 16; ++r)                                            \
      sa_[kv_][r] = bf2f((u16)BV[kv_ * 2 + (r >> 3)][r & 7]);               \
  __builtin_amdgcn_s_setprio(1);                                            \
  _Pragma("unroll")                                                         \
  for (int ki = 0; ki < 4; ++ki) {                                          \
    _Pragma("unroll")                                                       \
    for (int kv_ = 0; kv_ < 2; ++kv_) {                                     \
      s16x8 kf = *(const s16x8*)&KB[(kv_ * 32 + l31) * 64 +                 \
                                    (((ki * 2 + hi) ^ (l31 & 7)) * 8)];     \
      sa_[kv_] = __builtin_amdgcn_mfma_f32_32x32x16_bf16(kf, qf[ki],        \
                                                         sa_[kv_], 0, 0, 0);\
    }                                                                       \
  }                                                                         \
  __builtin_amdgcn_s_setprio(0);                                            \
  float p_[32];                                                             \
  _Pragma("unroll")                                                         \
  for (int kv_ = 0; kv_ < 2; ++kv_)                                         \
    _Pragma("unroll")                                                       \
    for (int r = 0; r < 16; ++r)                                            \
      p_[kv_ * 16 + r] = exp2f(sa_[kv_][r]);                                \
  float tm_[16];                                                            \
  _Pragma("unroll")                                                         \
  for (int i = 0; i < 16; ++i) tm_[i] = p_[i] + p_[i + 16];                 \
  _Pragma("unroll")                                                         \
  for (int off = 8; off >= 1; off >>= 1)                                    \
    _Pragma("unroll")                                                       \
    for (int i = 0; i < off; ++i) tm_[i] += tm_[i + off];                   \
  l_run += tm_[0];                                                          \
  union { uint32_t u[4]; s16x8 v; } pa_[4];                                 \
  _Pragma("unroll")                                                         \
  for (int s = 0; s < 4; ++s)                                               \
    _Pragma("unroll")                                                       \
    for (int w = 0; w < 4; ++w)                                             \
      pa_[s].u[w] = cvt_pk_bf16(p_[(s >> 1) * 16 + (s & 1) * 8 + 2 * w],    \
                                p_[(s >> 1) * 16 + (s & 1) * 8 + 2 * w + 1]);\
  __builtin_amdgcn_s_setprio(1);                                            \
  _Pragma("unroll")                                                         \
  for (int s = 0; s < 4; ++s) {                                             \
    _Pragma("unroll")                                                       \
    for (int dt = 0; dt < 2; ++dt) {                                        \
      s16x8 vf = *(const s16x8*)&VB[(dt * 32 + l31) * 64 +                  \
                                    (((s * 2 + hi) ^ (l31 & 7)) * 8)];      \
      oacc[dt] = __builtin_amdgcn_mfma_f32_32x32x16_bf16(vf, pa_[s].v,      \
                                                         oacc[dt], 0, 0, 0);\
    }                                                                       \
  }                                                                         \
  __builtin_amdgcn_s_setprio(0);                                            \
} while (0)

__global__ __launch_bounds__(256, 3) void k_attn(
    const u16* __restrict__ qkv, const u16* __restrict__ vtg,
    const u16* __restrict__ biasb, u16* __restrict__ ctx) {
  __shared__ u16 Kl[3][64 * 64];
  __shared__ u16 Vl[3][64 * 64];
  int bid = blockIdx.x;
  int swz = (bid & 7) * 96 + (bid >> 3);   // 768 = 8*96, bijective
  int h = swz % 12;
  int bq = swz / 12;        // 0..63
  int qt = bq & 15;
  int b = bq >> 4;
  int bh = b * 12 + h;
  int t = threadIdx.x, wave = t >> 6, lane = t & 63;
  int l31 = lane & 31, hi = lane >> 5;
  const size_t BHKD = (size_t)48 * 2048 * 64;
  const u16* Q = qkv + (size_t)bh * 2048 * 64;
  const u16* Kg = Q + BHKD;
  const u16* Vt = vtg + (size_t)bh * 64 * 2048;
  int qrow = qt * 128 + wave * 32 + l31;
  const u16* Bgl = biasb + ((size_t)b * 2048 + qrow) * 2048 + hi * 8;
  s16x8 qf[4];
#pragma unroll
  for (int ki = 0; ki < 4; ++ki)
    qf[ki] = *(const s16x8*)&Q[(size_t)qrow * 64 + ki * 16 + hi * 8];
  f32x16 oacc[2];
#pragma unroll
  for (int r = 0; r < 16; ++r) { oacc[0][r] = 0.f; oacc[1][r] = 0.f; }
  float l_run = 0.f;

  // prologue: stage tiles 0 and 1; wait only tile 0 (vmcnt leaves 4 of t=1)
  STAGE_KV(Kl[0], Vl[0], 0);
  STAGE_KV(Kl[1], Vl[1], 1);
  asm volatile("s_waitcnt vmcnt(4)" ::: "memory");
  __builtin_amdgcn_s_barrier();
  __builtin_amdgcn_sched_barrier(0);

  int cur = 0;
#pragma unroll 1
  for (int kt = 0; kt < 32; ++kt) {
    s16x8 bv_[4];
    LOAD_B(bv_, kt);                      // bias first (drained pre-barrier)
    int nb = cur + 2; if (nb >= 3) nb -= 3;
    if (kt + 2 < 32) STAGE_KV(Kl[nb], Vl[nb], kt + 2);
    COMPUTE_TILE(Kl[cur], Vl[cur], bv_);
    // keep the newest stage (kt+2, 4 loads) in flight across the barrier;
    // everything older (bias + stage kt+1) is provably drained.
    asm volatile("s_waitcnt vmcnt(4)" ::: "memory");
    __builtin_amdgcn_sched_barrier(0);
    __builtin_amdgcn_s_barrier();
    __builtin_amdgcn_sched_barrier(0);
    cur = cur + 1; if (cur >= 3) cur = 0;
  }
  float l_tot = l_run + __shfl_xor(l_run, 32);
  float inv = 1.0f / l_tot;
  size_t obase = ((size_t)b * 2048 + qrow) * 768 + h * 64;
#pragma unroll
  for (int dt = 0; dt < 2; ++dt) {
#pragma unroll
    for (int g = 0; g < 4; ++g) {
      s16x4 o4;
#pragma unroll
      for (int j = 0; j < 4; ++j)
        o4[j] = (short)f2bf(oacc[dt][g * 4 + j] * inv);
      *(s16x4*)&ctx[obase + dt * 32 + g * 8 + hi * 4] = o4;
    }
  }
}

// ---------------- Kernel 5: proj GEMM [8192,768] x [768,768] + b ---------
__global__ __launch_bounds__(256) void k_gemm_proj(
    const u16* __restrict__ A, const u16* __restrict__ Bt,
    const float* __restrict__ bias, float* __restrict__ out) {
  __shared__ u16 Al[128 * 64];
  __shared__ u16 Bl[128 * 64];
  int mt = blockIdx.x, nt = blockIdx.y;
  int t = threadIdx.x, wave = t >> 6, lane = t & 63;
  int lr = lane & 15, lg = lane >> 4;
  f32x4 acc[4][4];
#pragma unroll
  for (int i = 0; i < 4; ++i)
#pragma unroll
    for (int j = 0; j < 4; ++j) acc[i][j] = (f32x4){0.f, 0.f, 0.f, 0.f};
  const size_t Ab = (size_t)mt * 128 * 768;
  const size_t Bb = (size_t)nt * 128 * 768;
  int wr = (wave >> 1) * 64, wc = (wave & 1) * 64;
  for (int kt = 0; kt < 12; ++kt) {
#pragma unroll
    for (int c = 0; c < 4; ++c) {
      int q = c * 256 + t;
      int row = q >> 3, ch = q & 7;
      int sc = ch ^ (row & 7);
      GLD_LDS16(A + Ab + (size_t)row * 768 + kt * 64 + sc * 8,
                &Al[(size_t)(c * 256 + wave * 64) * 8]);
      GLD_LDS16(Bt + Bb + (size_t)row * 768 + kt * 64 + sc * 8,
                &Bl[(size_t)(c * 256 + wave * 64) * 8]);
    }
    __syncthreads();
#pragma unroll
    for (int ki = 0; ki < 2; ++ki) {
      s16x8 af[4], bf[4];
#pragma unroll
      for (int mi = 0; mi < 4; ++mi)
        af[mi] = *(const s16x8*)&Al[(wr + mi * 16 + lr) * 64 +
                                    (((ki * 4 + lg) ^ (lr & 7)) * 8)];
#pragma unroll
      for (int ni = 0; ni < 4; ++ni)
        bf[ni] = *(const s16x8*)&Bl[(wc + ni * 16 + lr) * 64 +
                                    (((ki * 4 + lg) ^ (lr & 7)) * 8)];
#pragma unroll
      for (int mi = 0; mi < 4; ++mi)
#pragma unroll
        for (int ni = 0; ni < 4; ++ni)
          acc[mi][ni] = __builtin_amdgcn_mfma_f32_16x16x32_bf16(
              af[mi], bf[ni], acc[mi][ni], 0, 0, 0);
    }
    __syncthreads();
  }
#pragma unroll
  for (int ni = 0; ni < 4; ++ni) {
    int col = wc + ni * 16 + lr;
    int n = nt * 128 + col;
    float bs = bias[n];
#pragma unroll
    for (int mi = 0; mi < 4; ++mi) {
#pragma unroll
      for (int j = 0; j < 4; ++j) {
        int row = wr + mi * 16 + lg * 4 + j;
        out[(size_t)(mt * 128 + row) * 768 + n] = acc[mi][ni][j] + bs;
      }
    }
  }
}

extern "C" void kernel_launch(void* const* d_in, const int* in_sizes, int n_in,
                              void* d_out, int out_size, void* d_ws, size_t ws_size,
                              hipStream_t stream) {
  const float* x      = (const float*)d_in[0];
  const float* pos    = (const float*)d_in[1];
  const float* bias   = (const float*)d_in[2];
  const float* ln_g   = (const float*)d_in[3];
  const float* ln_b   = (const float*)d_in[4];
  const float* qkv_w  = (const float*)d_in[5];
  const float* qkv_b  = (const float*)d_in[6];
  const float* proj_w = (const float*)d_in[7];
  const float* proj_b = (const float*)d_in[8];
  float* out = (float*)d_out;

  char* ws = (char*)d_ws;
  u16* xp      = (u16*)ws;              ws += 12582912;   // [8192][768]
  u16* qkv_wt  = (u16*)ws;              ws += 3538944;    // [2304][768]
  u16* proj_wt = (u16*)ws;              ws += 1179648;    // [768][768]
  u16* qkvbuf  = (u16*)ws;              ws += 25165824;   // Q,K [B,H,K,D]
  u16* ctx     = (u16*)ws;              ws += 12582912;   // [8192][768]
  u16* vtg     = (u16*)ws;              ws += 12582912;   // [B,H,D,K]
  u16* biasb   = (u16*)ws;              ws += 33554432;   // [4][2048][2048] bf16

  k_bcast<<<8192, 256, 0, stream>>>(bias, biasb);
  k_ln<<<8192, 256, 0, stream>>>(x, pos, ln_g, ln_b, xp);
  k_tr<<<dim3(72, 24), 256, 0, stream>>>(qkv_w, qkv_wt, 768, 2304);
  k_tr<<<dim3(24, 24), 256, 0, stream>>>(proj_w, proj_wt, 768, 768);
  k_gemm_qkv<<<dim3(64, 18), 256, 0, stream>>>(xp, qkv_wt, qkv_b, qkvbuf, vtg);
  k_attn<<<768, 256, 0, stream>>>(qkvbuf, vtg, biasb, ctx);
  k_gemm_proj<<<dim3(64, 6), 256, 0, stream>>>(ctx, proj_wt, proj_b, out);
}

// Round 16
// 200.612 us; speedup vs baseline: 1.3150x; 1.0011x over previous
//
#include <hip/hip_runtime.h>
#include <hip/hip_bf16.h>
#include <stdint.h>

typedef __attribute__((ext_vector_type(4))) float f32x4;
typedef __attribute__((ext_vector_type(16))) float f32x16;
typedef __attribute__((ext_vector_type(8))) short s16x8;
typedef __attribute__((ext_vector_type(4))) short s16x4;
typedef uint16_t u16;

#define DEV __device__ __forceinline__

static DEV u16 f2bf(float f) {
  union { float f; uint32_t u; } v; v.f = f;
  uint32_t r = v.u + 0x7fffu + ((v.u >> 16) & 1u);
  return (u16)(r >> 16);
}

static DEV float bf2f(u16 x) {
  union { uint32_t u; float f; } v; v.u = ((uint32_t)x) << 16;
  return v.f;
}

static DEV uint32_t cvt_pk_bf16(float lo, float hi) {
  uint32_t r;
  asm("v_cvt_pk_bf16_f32 %0, %1, %2" : "=v"(r) : "v"(lo), "v"(hi));
  return r;
}

#define GLD_LDS16(gp, lp) __builtin_amdgcn_global_load_lds( \
    (const __attribute__((address_space(1))) void*)(gp),    \
    (__attribute__((address_space(3))) void*)(lp), 16, 0, 0)

// ---------------- Kernel 1: LayerNorm + pos_embed -> bf16 ----------------
__global__ __launch_bounds__(256) void k_ln(
    const float* __restrict__ x, const float* __restrict__ pos,
    const float* __restrict__ g, const float* __restrict__ be,
    u16* __restrict__ xp) {
  int row = blockIdx.x;
  size_t base = (size_t)row * 768;
  int t = threadIdx.x;
  float v0 = x[base + t], v1 = x[base + t + 256], v2 = x[base + t + 512];
  float s = v0 + v1 + v2;
  float ss = v0 * v0 + v1 * v1 + v2 * v2;
#pragma unroll
  for (int off = 1; off < 64; off <<= 1) {
    s += __shfl_xor(s, off);
    ss += __shfl_xor(ss, off);
  }
  __shared__ float red[8];
  int wave = t >> 6, lane = t & 63;
  if (lane == 0) { red[wave] = s; red[4 + wave] = ss; }
  __syncthreads();
  float tot = red[0] + red[1] + red[2] + red[3];
  float tss = red[4] + red[5] + red[6] + red[7];
  float mu = tot * (1.0f / 768.0f);
  float var = tss * (1.0f / 768.0f) - mu * mu;
  float rs = rsqrtf(var + 1e-5f);
  float vv[3] = {v0, v1, v2};
#pragma unroll
  for (int i = 0; i < 3; ++i) {
    int c = t + i * 256;
    float val = (vv[i] - mu) * rs * g[c] + be[c] + pos[base + c];
    xp[base + c] = f2bf(val);
  }
}

// ---------------- Kernel 2: transpose + cast f32[K][N] -> bf16[N][K] -----
__global__ __launch_bounds__(256) void k_tr(
    const float* __restrict__ in, u16* __restrict__ out, int K, int N) {
  __shared__ float tile[32][33];
  int n0 = blockIdx.x * 32, k0 = blockIdx.y * 32;
  int tx = threadIdx.x & 31, ty = threadIdx.x >> 5;
#pragma unroll
  for (int r = ty; r < 32; r += 8)
    tile[r][tx] = in[(size_t)(k0 + r) * N + n0 + tx];
  __syncthreads();
#pragma unroll
  for (int r = ty; r < 32; r += 8)
    out[(size_t)(n0 + r) * K + k0 + tx] = f2bf(tile[tx][r]);
}

// ---------------- Kernel 3: QKV GEMM + fused bias cast -------------------
// Prologue: grid-stride cast of rel_pos_bias f32 -> bf16*log2e (biasb).
// GEMM: Q,K -> qkv [which][B,H,K,D]; V -> vtg [B,H,D,K] (fused transpose).
// Q PRE-SCALED by 0.125*log2(e).
__global__ __launch_bounds__(256) void k_gemm_qkv(
    const u16* __restrict__ A, const u16* __restrict__ Bt,
    const float* __restrict__ bias, u16* __restrict__ qkv,
    u16* __restrict__ vtg, const float* __restrict__ biasf,
    u16* __restrict__ biasb) {
  __shared__ u16 Al[128 * 64];
  __shared__ u16 Bl[128 * 64];
  const size_t BHKD = (size_t)48 * 2048 * 64;
  int mt = blockIdx.x, nt = blockIdx.y;
  int t = threadIdx.x, wave = t >> 6, lane = t & 63;
  int lr = lane & 15, lg = lane >> 4;
  // ---- fused bias cast (runs before GEMM; biasb consumed by k_attn) ----
  {
    size_t tid = ((size_t)(nt * 64 + mt) * 256 + t) * 8;
    size_t stride = (size_t)1152 * 256 * 8;
    const size_t NB = (size_t)4 * 2048 * 2048;
    for (size_t i = tid; i < NB; i += stride) {
      f32x4 a = *(const f32x4*)(biasf + i);
      f32x4 b = *(const f32x4*)(biasf + i + 4);
      s16x8 o;
#pragma unroll
      for (int j = 0; j < 4; ++j) o[j] = (short)f2bf(a[j] * 1.4426950409f);
#pragma unroll
      for (int j = 0; j < 4; ++j) o[4 + j] = (short)f2bf(b[j] * 1.4426950409f);
      *(s16x8*)(biasb + i) = o;
    }
  }
  f32x4 acc[4][4];
#pragma unroll
  for (int i = 0; i < 4; ++i)
#pragma unroll
    for (int j = 0; j < 4; ++j) acc[i][j] = (f32x4){0.f, 0.f, 0.f, 0.f};
  const size_t Ab = (size_t)mt * 128 * 768;
  const size_t Bb = (size_t)nt * 128 * 768;
  int wr = (wave >> 1) * 64, wc = (wave & 1) * 64;
  for (int kt = 0; kt < 12; ++kt) {
#pragma unroll
    for (int c = 0; c < 4; ++c) {
      int q = c * 256 + t;
      int row = q >> 3, ch = q & 7;
      int sc = ch ^ (row & 7);
      GLD_LDS16(A + Ab + (size_t)row * 768 + kt * 64 + sc * 8,
                &Al[(size_t)(c * 256 + wave * 64) * 8]);
      GLD_LDS16(Bt + Bb + (size_t)row * 768 + kt * 64 + sc * 8,
                &Bl[(size_t)(c * 256 + wave * 64) * 8]);
    }
    __syncthreads();
#pragma unroll
    for (int ki = 0; ki < 2; ++ki) {
      s16x8 af[4], bf[4];
#pragma unroll
      for (int mi = 0; mi < 4; ++mi)
        af[mi] = *(const s16x8*)&Al[(wr + mi * 16 + lr) * 64 +
                                    (((ki * 4 + lg) ^ (lr & 7)) * 8)];
#pragma unroll
      for (int ni = 0; ni < 4; ++ni)
        bf[ni] = *(const s16x8*)&Bl[(wc + ni * 16 + lr) * 64 +
                                    (((ki * 4 + lg) ^ (lr & 7)) * 8)];
#pragma unroll
      for (int mi = 0; mi < 4; ++mi)
#pragma unroll
        for (int ni = 0; ni < 4; ++ni)
          acc[mi][ni] = __builtin_amdgcn_mfma_f32_16x16x32_bf16(
              af[mi], bf[ni], acc[mi][ni], 0, 0, 0);
    }
    __syncthreads();
  }
  int which0 = (nt * 128) / 768;           // block-uniform (768 = 6*128)
  float qscale = (which0 == 0) ? 0.1803368801f : 1.0f;
#pragma unroll
  for (int ni = 0; ni < 4; ++ni) {
    int col = wc + ni * 16 + lr;
    int n = nt * 128 + col;
    int which = n / 768, cc = n % 768;
    int h = cc >> 6, d = cc & 63;
    float bs = bias[n];
    if (which == 2) {
#pragma unroll
      for (int mi = 0; mi < 4; ++mi) {
        int m0 = mt * 128 + wr + mi * 16 + lg * 4;
        int b = m0 >> 11, kp0 = m0 & 2047;
        s16x4 o4;
#pragma unroll
        for (int j = 0; j < 4; ++j) o4[j] = (short)f2bf(acc[mi][ni][j] + bs);
        *(s16x4*)&vtg[((size_t)(b * 12 + h) * 64 + d) * 2048 + kp0] = o4;
      }
    } else {
#pragma unroll
      for (int mi = 0; mi < 4; ++mi) {
#pragma unroll
        for (int j = 0; j < 4; ++j) {
          int row = wr + mi * 16 + lg * 4 + j;
          int m = mt * 128 + row;
          int b = m >> 11, kp = m & 2047;
          size_t dst = (size_t)which * BHKD +
                       (((size_t)b * 12 + h) * 2048 + kp) * 64 + d;
          qkv[dst] = f2bf((acc[mi][ni][j] + bs) * qscale);
        }
      }
    }
  }
}

// ---------------- Kernel 4: flash attention (bf16 bias + lacc MFMA) ------
// R15 pipeline; l-sum moved to the matrix pipe: lacc = mfma(ones, pa, lacc)
// (every output row equals sum_kv P -> lacc[0] is the denominator). Deletes
// the 31-add VALU tree + final shfl.
#define STAGE_KV(KB, VB, ktt) do {                                          \
  _Pragma("unroll")                                                         \
  for (int c_ = 0; c_ < 2; ++c_) {                                          \
    int q_ = c_ * 256 + t; int r_ = q_ >> 3, ch_ = q_ & 7;                  \
    int sc_ = ch_ ^ (r_ & 7);                                               \
    int gk_ = (r_ & 0x33) | ((r_ & 4) << 1) | ((r_ & 8) >> 1);              \
    GLD_LDS16(Kg + ((size_t)((ktt) * 64 + gk_)) * 64 + sc_ * 8,             \
              &KB[(c_ * 256 + wave * 64) * 8]);                             \
    GLD_LDS16(Vt + (size_t)r_ * 2048 + (ktt) * 64 + sc_ * 8,                \
              &VB[(c_ * 256 + wave * 64) * 8]);                             \
  }                                                                         \
} while (0)

#define LOAD_B(BR, ktt) do {                                                \
  const u16* bp_ = Bgl + (ktt) * 64;                                        \
  BR[0] = *(const s16x8*)(bp_);                                             \
  BR[1] = *(const s16x8*)(bp_ + 16);                                        \
  BR[2] = *(const s16x8*)(bp_ + 32);                                        \
  BR[3] = *(const s16x8*)(bp_ + 48);                                        \
} while (0)

#define COMPUTE_TILE(KB, VB, BV) do {                                       \
  f32x16 sa_[2];                                                            \
  _Pragma("unroll")                                                         \
  for (int kv_ = 0; kv_ < 2; ++kv_)                                         \
    _Pragma("unroll")                                                       \
    for (int r = 0; r < 16; ++r)                                            \
      sa_[kv_][r] = bf2f((u16)BV[kv_ * 2 + (r >> 3)][r & 7]);               \
  __builtin_amdgcn_s_setprio(1);                                            \
  _Pragma("unroll")                                                         \
  for (int ki = 0; ki < 4; ++ki) {                                          \
    _Pragma("unroll")                                                       \
    for (int kv_ = 0; kv_ < 2; ++kv_) {                                     \
      s16x8 kf = *(const s16x8*)&KB[(kv_ * 32 + l31) * 64 +                 \
                                    (((ki * 2 + hi) ^ (l31 & 7)) * 8)];     \
      sa_[kv_] = __builtin_amdgcn_mfma_f32_32x32x16_bf16(kf, qf[ki],        \
                                                         sa_[kv_], 0, 0, 0);\
    }                                                                       \
  }                                                                         \
  __builtin_amdgcn_s_setprio(0);                                            \
  float p_[32];                                                             \
  _Pragma("unroll")                                                         \
  for (int kv_ = 0; kv_ < 2; ++kv_)                                         \
    _Pragma("unroll")                                                       \
    for (int r = 0; r < 16; ++r)                                            \
      p_[kv_ * 16 + r] = exp2f(sa_[kv_][r]);                                \
  union { uint32_t u[4]; s16x8 v; } pa_[4];                                 \
  _Pragma("unroll")                                                         \
  for (int s = 0; s < 4; ++s)                                               \
    _Pragma("unroll")                                                       \
    for (int w = 0; w < 4; ++w)                                             \
      pa_[s].u[w] = cvt_pk_bf16(p_[(s >> 1) * 16 + (s & 1) * 8 + 2 * w],    \
                                p_[(s >> 1) * 16 + (s & 1) * 8 + 2 * w + 1]);\
  __builtin_amdgcn_s_setprio(1);                                            \
  _Pragma("unroll")                                                         \
  for (int s = 0; s < 4; ++s) {                                             \
    lacc = __builtin_amdgcn_mfma_f32_32x32x16_bf16(onesv, pa_[s].v,         \
                                                   lacc, 0, 0, 0);          \
    _Pragma("unroll")                                                       \
    for (int dt = 0; dt < 2; ++dt) {                                        \
      s16x8 vf = *(const s16x8*)&VB[(dt * 32 + l31) * 64 +                  \
                                    (((s * 2 + hi) ^ (l31 & 7)) * 8)];      \
      oacc[dt] = __builtin_amdgcn_mfma_f32_32x32x16_bf16(vf, pa_[s].v,      \
                                                         oacc[dt], 0, 0, 0);\
    }                                                                       \
  }                                                                         \
  __builtin_amdgcn_s_setprio(0);                                            \
} while (0)

__global__ __launch_bounds__(256, 2) void k_attn(
    const u16* __restrict__ qkv, const u16* __restrict__ vtg,
    const u16* __restrict__ biasb, u16* __restrict__ ctx) {
  __shared__ u16 Kl[3][64 * 64];
  __shared__ u16 Vl[3][64 * 64];
  int bid = blockIdx.x;
  int swz = (bid & 7) * 96 + (bid >> 3);   // 768 = 8*96, bijective
  int h = swz % 12;
  int bq = swz / 12;        // 0..63
  int qt = bq & 15;
  int b = bq >> 4;
  int bh = b * 12 + h;
  int t = threadIdx.x, wave = t >> 6, lane = t & 63;
  int l31 = lane & 31, hi = lane >> 5;
  const size_t BHKD = (size_t)48 * 2048 * 64;
  const u16* Q = qkv + (size_t)bh * 2048 * 64;
  const u16* Kg = Q + BHKD;
  const u16* Vt = vtg + (size_t)bh * 64 * 2048;
  int qrow = qt * 128 + wave * 32 + l31;
  const u16* Bgl = biasb + ((size_t)b * 2048 + qrow) * 2048 + hi * 8;
  s16x8 qf[4];
#pragma unroll
  for (int ki = 0; ki < 4; ++ki)
    qf[ki] = *(const s16x8*)&Q[(size_t)qrow * 64 + ki * 16 + hi * 8];
  s16x8 onesv;
#pragma unroll
  for (int i = 0; i < 8; ++i) onesv[i] = (short)0x3F80;   // bf16 1.0
  f32x16 oacc[2], lacc;
#pragma unroll
  for (int r = 0; r < 16; ++r) { oacc[0][r] = 0.f; oacc[1][r] = 0.f; lacc[r] = 0.f; }

  // prologue: stage tiles 0 and 1; wait only tile 0 (vmcnt leaves 4 of t=1)
  STAGE_KV(Kl[0], Vl[0], 0);
  STAGE_KV(Kl[1], Vl[1], 1);
  asm volatile("s_waitcnt vmcnt(4)" ::: "memory");
  __builtin_amdgcn_s_barrier();
  __builtin_amdgcn_sched_barrier(0);

  int cur = 0;
#pragma unroll 1
  for (int kt = 0; kt < 32; ++kt) {
    s16x8 bv_[4];
    LOAD_B(bv_, kt);                      // bias first (drained pre-barrier)
    int nb = cur + 2; if (nb >= 3) nb -= 3;
    if (kt + 2 < 32) STAGE_KV(Kl[nb], Vl[nb], kt + 2);
    COMPUTE_TILE(Kl[cur], Vl[cur], bv_);
    // keep the newest stage (kt+2, 4 loads) in flight across the barrier;
    // everything older (bias + stage kt+1) is provably drained.
    asm volatile("s_waitcnt vmcnt(4)" ::: "memory");
    __builtin_amdgcn_sched_barrier(0);
    __builtin_amdgcn_s_barrier();
    __builtin_amdgcn_sched_barrier(0);
    cur = cur + 1; if (cur >= 3) cur = 0;
  }
  float inv = 1.0f / lacc[0];
  size_t obase = ((size_t)b * 2048 + qrow) * 768 + h * 64;
#pragma unroll
  for (int dt = 0; dt < 2; ++dt) {
#pragma unroll
    for (int g = 0; g < 4; ++g) {
      s16x4 o4;
#pragma unroll
      for (int j = 0; j < 4; ++j)
        o4[j] = (short)f2bf(oacc[dt][g * 4 + j] * inv);
      *(s16x4*)&ctx[obase + dt * 32 + g * 8 + hi * 4] = o4;
    }
  }
}

// ---------------- Kernel 5: proj GEMM [8192,768] x [768,768] + b ---------
__global__ __launch_bounds__(256) void k_gemm_proj(
    const u16* __restrict__ A, const u16* __restrict__ Bt,
    const float* __restrict__ bias, float* __restrict__ out) {
  __shared__ u16 Al[128 * 64];
  __shared__ u16 Bl[128 * 64];
  int mt = blockIdx.x, nt = blockIdx.y;
  int t = threadIdx.x, wave = t >> 6, lane = t & 63;
  int lr = lane & 15, lg = lane >> 4;
  f32x4 acc[4][4];
#pragma unroll
  for (int i = 0; i < 4; ++i)
#pragma unroll
    for (int j = 0; j < 4; ++j) acc[i][j] = (f32x4){0.f, 0.f, 0.f, 0.f};
  const size_t Ab = (size_t)mt * 128 * 768;
  const size_t Bb = (size_t)nt * 128 * 768;
  int wr = (wave >> 1) * 64, wc = (wave & 1) * 64;
  for (int kt = 0; kt < 12; ++kt) {
#pragma unroll
    for (int c = 0; c < 4; ++c) {
      int q = c * 256 + t;
      int row = q >> 3, ch = q & 7;
      int sc = ch ^ (row & 7);
      GLD_LDS16(A + Ab + (size_t)row * 768 + kt * 64 + sc * 8,
                &Al[(size_t)(c * 256 + wave * 64) * 8]);
      GLD_LDS16(Bt + Bb + (size_t)row * 768 + kt * 64 + sc * 8,
                &Bl[(size_t)(c * 256 + wave * 64) * 8]);
    }
    __syncthreads();
#pragma unroll
    for (int ki = 0; ki < 2; ++ki) {
      s16x8 af[4], bf[4];
#pragma unroll
      for (int mi = 0; mi < 4; ++mi)
        af[mi] = *(const s16x8*)&Al[(wr + mi * 16 + lr) * 64 +
                                    (((ki * 4 + lg) ^ (lr & 7)) * 8)];
#pragma unroll
      for (int ni = 0; ni < 4; ++ni)
        bf[ni] = *(const s16x8*)&Bl[(wc + ni * 16 + lr) * 64 +
                                    (((ki * 4 + lg) ^ (lr & 7)) * 8)];
#pragma unroll
      for (int mi = 0; mi < 4; ++mi)
#pragma unroll
        for (int ni = 0; ni < 4; ++ni)
          acc[mi][ni] = __builtin_amdgcn_mfma_f32_16x16x32_bf16(
              af[mi], bf[ni], acc[mi][ni], 0, 0, 0);
    }
    __syncthreads();
  }
#pragma unroll
  for (int ni = 0; ni < 4; ++ni) {
    int col = wc + ni * 16 + lr;
    int n = nt * 128 + col;
    float bs = bias[n];
#pragma unroll
    for (int mi = 0; mi < 4; ++mi) {
#pragma unroll
      for (int j = 0; j < 4; ++j) {
        int row = wr + mi * 16 + lg * 4 + j;
        out[(size_t)(mt * 128 + row) * 768 + n] = acc[mi][ni][j] + bs;
      }
    }
  }
}

extern "C" void kernel_launch(void* const* d_in, const int* in_sizes, int n_in,
                              void* d_out, int out_size, void* d_ws, size_t ws_size,
                              hipStream_t stream) {
  const float* x      = (const float*)d_in[0];
  const float* pos    = (const float*)d_in[1];
  const float* bias   = (const float*)d_in[2];
  const float* ln_g   = (const float*)d_in[3];
  const float* ln_b   = (const float*)d_in[4];
  const float* qkv_w  = (const float*)d_in[5];
  const float* qkv_b  = (const float*)d_in[6];
  const float* proj_w = (const float*)d_in[7];
  const float* proj_b = (const float*)d_in[8];
  float* out = (float*)d_out;

  char* ws = (char*)d_ws;
  u16* xp      = (u16*)ws;              ws += 12582912;   // [8192][768]
  u16* qkv_wt  = (u16*)ws;              ws += 3538944;    // [2304][768]
  u16* proj_wt = (u16*)ws;              ws += 1179648;    // [768][768]
  u16* qkvbuf  = (u16*)ws;              ws += 25165824;   // Q,K [B,H,K,D]
  u16* ctx     = (u16*)ws;              ws += 12582912;   // [8192][768]
  u16* vtg     = (u16*)ws;              ws += 12582912;   // [B,H,D,K]
  u16* biasb   = (u16*)ws;              ws += 33554432;   // [4][2048][2048] bf16

  k_ln<<<8192, 256, 0, stream>>>(x, pos, ln_g, ln_b, xp);
  k_tr<<<dim3(72, 24), 256, 0, stream>>>(qkv_w, qkv_wt, 768, 2304);
  k_tr<<<dim3(24, 24), 256, 0, stream>>>(proj_w, proj_wt, 768, 768);
  k_gemm_qkv<<<dim3(64, 18), 256, 0, stream>>>(xp, qkv_wt, qkv_b, qkvbuf, vtg,
                                               bias, biasb);
  k_attn<<<768, 256, 0, stream>>>(qkvbuf, vtg, biasb, ctx);
  k_gemm_proj<<<dim3(64, 6), 256, 0, stream>>>(ctx, proj_wt, proj_b, out);
}

// Round 18
// 183.464 us; speedup vs baseline: 1.4379x; 1.0935x over previous
//
#include <hip/hip_runtime.h>
#include <hip/hip_bf16.h>
#include <stdint.h>

typedef __attribute__((ext_vector_type(4))) float f32x4;
typedef __attribute__((ext_vector_type(16))) float f32x16;
typedef __attribute__((ext_vector_type(8))) short s16x8;
typedef __attribute__((ext_vector_type(4))) short s16x4;
typedef uint16_t u16;

#define DEV __device__ __forceinline__

static DEV u16 f2bf(float f) {
  union { float f; uint32_t u; } v; v.f = f;
  uint32_t r = v.u + 0x7fffu + ((v.u >> 16) & 1u);
  return (u16)(r >> 16);
}

static DEV float bf2f(u16 x) {
  union { uint32_t u; float f; } v; v.u = ((uint32_t)x) << 16;
  return v.f;
}

static DEV uint32_t cvt_pk_bf16(float lo, float hi) {
  uint32_t r;
  asm("v_cvt_pk_bf16_f32 %0, %1, %2" : "=v"(r) : "v"(lo), "v"(hi));
  return r;
}

// bare 2^x via the compiler-visible intrinsic (hazard-safe). R17's raw
// inline-asm v_exp_f32 hid the TRANS-op read hazard from the compiler's
// hazard recognizer -> stale-register reads (absmax 2.6e-2). The builtin
// emits v_exp_f32 WITH proper wait states; fallback asm carries s_nop 1.
#if defined(__has_builtin) && __has_builtin(__builtin_amdgcn_exp2f)
static DEV float exp2_fast(float x) { return __builtin_amdgcn_exp2f(x); }
#else
static DEV float exp2_fast(float x) {
  float r;
  asm("v_exp_f32 %0, %1\n\ts_nop 1" : "=v"(r) : "v"(x));
  return r;
}
#endif

#define GLD_LDS16(gp, lp) __builtin_amdgcn_global_load_lds( \
    (const __attribute__((address_space(1))) void*)(gp),    \
    (__attribute__((address_space(3))) void*)(lp), 16, 0, 0)

// ---------------- Kernel 1: LayerNorm + pos_embed -> bf16 ----------------
__global__ __launch_bounds__(256) void k_ln(
    const float* __restrict__ x, const float* __restrict__ pos,
    const float* __restrict__ g, const float* __restrict__ be,
    u16* __restrict__ xp) {
  int row = blockIdx.x;
  size_t base = (size_t)row * 768;
  int t = threadIdx.x;
  float v0 = x[base + t], v1 = x[base + t + 256], v2 = x[base + t + 512];
  float s = v0 + v1 + v2;
  float ss = v0 * v0 + v1 * v1 + v2 * v2;
#pragma unroll
  for (int off = 1; off < 64; off <<= 1) {
    s += __shfl_xor(s, off);
    ss += __shfl_xor(ss, off);
  }
  __shared__ float red[8];
  int wave = t >> 6, lane = t & 63;
  if (lane == 0) { red[wave] = s; red[4 + wave] = ss; }
  __syncthreads();
  float tot = red[0] + red[1] + red[2] + red[3];
  float tss = red[4] + red[5] + red[6] + red[7];
  float mu = tot * (1.0f / 768.0f);
  float var = tss * (1.0f / 768.0f) - mu * mu;
  float rs = rsqrtf(var + 1e-5f);
  float vv[3] = {v0, v1, v2};
#pragma unroll
  for (int i = 0; i < 3; ++i) {
    int c = t + i * 256;
    float val = (vv[i] - mu) * rs * g[c] + be[c] + pos[base + c];
    xp[base + c] = f2bf(val);
  }
}

// ---------------- Kernel 2: transpose + cast f32[K][N] -> bf16[N][K] -----
__global__ __launch_bounds__(256) void k_tr(
    const float* __restrict__ in, u16* __restrict__ out, int K, int N) {
  __shared__ float tile[32][33];
  int n0 = blockIdx.x * 32, k0 = blockIdx.y * 32;
  int tx = threadIdx.x & 31, ty = threadIdx.x >> 5;
#pragma unroll
  for (int r = ty; r < 32; r += 8)
    tile[r][tx] = in[(size_t)(k0 + r) * N + n0 + tx];
  __syncthreads();
#pragma unroll
  for (int r = ty; r < 32; r += 8)
    out[(size_t)(n0 + r) * K + k0 + tx] = f2bf(tile[tx][r]);
}

// ---------------- Kernel 3: QKV GEMM + fused bias cast -------------------
// Prologue: grid-stride cast of rel_pos_bias f32 -> bf16*log2e (biasb).
// GEMM: Q,K -> qkv [which][B,H,K,D]; V -> vtg [B,H,D,K] (fused transpose).
// Q PRE-SCALED by 0.125*log2(e).
__global__ __launch_bounds__(256) void k_gemm_qkv(
    const u16* __restrict__ A, const u16* __restrict__ Bt,
    const float* __restrict__ bias, u16* __restrict__ qkv,
    u16* __restrict__ vtg, const float* __restrict__ biasf,
    u16* __restrict__ biasb) {
  __shared__ u16 Al[128 * 64];
  __shared__ u16 Bl[128 * 64];
  const size_t BHKD = (size_t)48 * 2048 * 64;
  int mt = blockIdx.x, nt = blockIdx.y;
  int t = threadIdx.x, wave = t >> 6, lane = t & 63;
  int lr = lane & 15, lg = lane >> 4;
  // ---- fused bias cast (runs before GEMM; biasb consumed by k_attn) ----
  {
    size_t tid = ((size_t)(nt * 64 + mt) * 256 + t) * 8;
    size_t stride = (size_t)1152 * 256 * 8;
    const size_t NB = (size_t)4 * 2048 * 2048;
    for (size_t i = tid; i < NB; i += stride) {
      f32x4 a = *(const f32x4*)(biasf + i);
      f32x4 b = *(const f32x4*)(biasf + i + 4);
      s16x8 o;
#pragma unroll
      for (int j = 0; j < 4; ++j) o[j] = (short)f2bf(a[j] * 1.4426950409f);
#pragma unroll
      for (int j = 0; j < 4; ++j) o[4 + j] = (short)f2bf(b[j] * 1.4426950409f);
      *(s16x8*)(biasb + i) = o;
    }
  }
  f32x4 acc[4][4];
#pragma unroll
  for (int i = 0; i < 4; ++i)
#pragma unroll
    for (int j = 0; j < 4; ++j) acc[i][j] = (f32x4){0.f, 0.f, 0.f, 0.f};
  const size_t Ab = (size_t)mt * 128 * 768;
  const size_t Bb = (size_t)nt * 128 * 768;
  int wr = (wave >> 1) * 64, wc = (wave & 1) * 64;
  for (int kt = 0; kt < 12; ++kt) {
#pragma unroll
    for (int c = 0; c < 4; ++c) {
      int q = c * 256 + t;
      int row = q >> 3, ch = q & 7;
      int sc = ch ^ (row & 7);
      GLD_LDS16(A + Ab + (size_t)row * 768 + kt * 64 + sc * 8,
                &Al[(size_t)(c * 256 + wave * 64) * 8]);
      GLD_LDS16(Bt + Bb + (size_t)row * 768 + kt * 64 + sc * 8,
                &Bl[(size_t)(c * 256 + wave * 64) * 8]);
    }
    __syncthreads();
#pragma unroll
    for (int ki = 0; ki < 2; ++ki) {
      s16x8 af[4], bf[4];
#pragma unroll
      for (int mi = 0; mi < 4; ++mi)
        af[mi] = *(const s16x8*)&Al[(wr + mi * 16 + lr) * 64 +
                                    (((ki * 4 + lg) ^ (lr & 7)) * 8)];
#pragma unroll
      for (int ni = 0; ni < 4; ++ni)
        bf[ni] = *(const s16x8*)&Bl[(wc + ni * 16 + lr) * 64 +
                                    (((ki * 4 + lg) ^ (lr & 7)) * 8)];
#pragma unroll
      for (int mi = 0; mi < 4; ++mi)
#pragma unroll
        for (int ni = 0; ni < 4; ++ni)
          acc[mi][ni] = __builtin_amdgcn_mfma_f32_16x16x32_bf16(
              af[mi], bf[ni], acc[mi][ni], 0, 0, 0);
    }
    __syncthreads();
  }
  int which0 = (nt * 128) / 768;           // block-uniform (768 = 6*128)
  float qscale = (which0 == 0) ? 0.1803368801f : 1.0f;
#pragma unroll
  for (int ni = 0; ni < 4; ++ni) {
    int col = wc + ni * 16 + lr;
    int n = nt * 128 + col;
    int which = n / 768, cc = n % 768;
    int h = cc >> 6, d = cc & 63;
    float bs = bias[n];
    if (which == 2) {
#pragma unroll
      for (int mi = 0; mi < 4; ++mi) {
        int m0 = mt * 128 + wr + mi * 16 + lg * 4;
        int b = m0 >> 11, kp0 = m0 & 2047;
        s16x4 o4;
#pragma unroll
        for (int j = 0; j < 4; ++j) o4[j] = (short)f2bf(acc[mi][ni][j] + bs);
        *(s16x4*)&vtg[((size_t)(b * 12 + h) * 64 + d) * 2048 + kp0] = o4;
      }
    } else {
#pragma unroll
      for (int mi = 0; mi < 4; ++mi) {
#pragma unroll
        for (int j = 0; j < 4; ++j) {
          int row = wr + mi * 16 + lg * 4 + j;
          int m = mt * 128 + row;
          int b = m >> 11, kp = m & 2047;
          size_t dst = (size_t)which * BHKD +
                       (((size_t)b * 12 + h) * 2048 + kp) * 64 + d;
          qkv[dst] = f2bf((acc[mi][ni][j] + bs) * qscale);
        }
      }
    }
  }
}

// ---------------- Kernel 4: flash attention (fast exp2, hazard-safe) -----
#define STAGE_KV(KB, VB, ktt) do {                                          \
  _Pragma("unroll")                                                         \
  for (int c_ = 0; c_ < 2; ++c_) {                                          \
    int q_ = c_ * 256 + t; int r_ = q_ >> 3, ch_ = q_ & 7;                  \
    int sc_ = ch_ ^ (r_ & 7);                                               \
    int gk_ = (r_ & 0x33) | ((r_ & 4) << 1) | ((r_ & 8) >> 1);              \
    GLD_LDS16(Kg + ((size_t)((ktt) * 64 + gk_)) * 64 + sc_ * 8,             \
              &KB[(c_ * 256 + wave * 64) * 8]);                             \
    GLD_LDS16(Vt + (size_t)r_ * 2048 + (ktt) * 64 + sc_ * 8,                \
              &VB[(c_ * 256 + wave * 64) * 8]);                             \
  }                                                                         \
} while (0)

#define LOAD_B(BR, ktt) do {                                                \
  const u16* bp_ = Bgl + (ktt) * 64;                                        \
  BR[0] = *(const s16x8*)(bp_);                                             \
  BR[1] = *(const s16x8*)(bp_ + 16);                                        \
  BR[2] = *(const s16x8*)(bp_ + 32);                                        \
  BR[3] = *(const s16x8*)(bp_ + 48);                                        \
} while (0)

#define COMPUTE_TILE(KB, VB, BV) do {                                       \
  f32x16 sa_[2];                                                            \
  _Pragma("unroll")                                                         \
  for (int kv_ = 0; kv_ < 2; ++kv_)                                         \
    _Pragma("unroll")                                                       \
    for (int r = 0; r < 16; ++r)                                            \
      sa_[kv_][r] = bf2f((u16)BV[kv_ * 2 + (r >> 3)][r & 7]);               \
  __builtin_amdgcn_s_setprio(1);                                            \
  _Pragma("unroll")                                                         \
  for (int ki = 0; ki < 4; ++ki) {                                          \
    _Pragma("unroll")                                                       \
    for (int kv_ = 0; kv_ < 2; ++kv_) {                                     \
      s16x8 kf = *(const s16x8*)&KB[(kv_ * 32 + l31) * 64 +                 \
                                    (((ki * 2 + hi) ^ (l31 & 7)) * 8)];     \
      sa_[kv_] = __builtin_amdgcn_mfma_f32_32x32x16_bf16(kf, qf[ki],        \
                                                         sa_[kv_], 0, 0, 0);\
    }                                                                       \
  }                                                                         \
  __builtin_amdgcn_s_setprio(0);                                            \
  float p_[32];                                                             \
  _Pragma("unroll")                                                         \
  for (int kv_ = 0; kv_ < 2; ++kv_)                                         \
    _Pragma("unroll")                                                       \
    for (int r = 0; r < 16; ++r)                                            \
      p_[kv_ * 16 + r] = exp2_fast(sa_[kv_][r]);                            \
  union { uint32_t u[4]; s16x8 v; } pa_[4];                                 \
  _Pragma("unroll")                                                         \
  for (int s = 0; s < 4; ++s)                                               \
    _Pragma("unroll")                                                       \
    for (int w = 0; w < 4; ++w)                                             \
      pa_[s].u[w] = cvt_pk_bf16(p_[(s >> 1) * 16 + (s & 1) * 8 + 2 * w],    \
                                p_[(s >> 1) * 16 + (s & 1) * 8 + 2 * w + 1]);\
  __builtin_amdgcn_s_setprio(1);                                            \
  _Pragma("unroll")                                                         \
  for (int s = 0; s < 4; ++s) {                                             \
    lacc = __builtin_amdgcn_mfma_f32_32x32x16_bf16(onesv, pa_[s].v,         \
                                                   lacc, 0, 0, 0);          \
    _Pragma("unroll")                                                       \
    for (int dt = 0; dt < 2; ++dt) {                                        \
      s16x8 vf = *(const s16x8*)&VB[(dt * 32 + l31) * 64 +                  \
                                    (((s * 2 + hi) ^ (l31 & 7)) * 8)];      \
      oacc[dt] = __builtin_amdgcn_mfma_f32_32x32x16_bf16(vf, pa_[s].v,      \
                                                         oacc[dt], 0, 0, 0);\
    }                                                                       \
  }                                                                         \
  __builtin_amdgcn_s_setprio(0);                                            \
} while (0)

__global__ __launch_bounds__(256, 2) void k_attn(
    const u16* __restrict__ qkv, const u16* __restrict__ vtg,
    const u16* __restrict__ biasb, u16* __restrict__ ctx) {
  __shared__ u16 Kl[3][64 * 64];
  __shared__ u16 Vl[3][64 * 64];
  int bid = blockIdx.x;
  int swz = (bid & 7) * 96 + (bid >> 3);   // 768 = 8*96, bijective
  int h = swz % 12;
  int bq = swz / 12;        // 0..63
  int qt = bq & 15;
  int b = bq >> 4;
  int bh = b * 12 + h;
  int t = threadIdx.x, wave = t >> 6, lane = t & 63;
  int l31 = lane & 31, hi = lane >> 5;
  const size_t BHKD = (size_t)48 * 2048 * 64;
  const u16* Q = qkv + (size_t)bh * 2048 * 64;
  const u16* Kg = Q + BHKD;
  const u16* Vt = vtg + (size_t)bh * 64 * 2048;
  int qrow = qt * 128 + wave * 32 + l31;
  const u16* Bgl = biasb + ((size_t)b * 2048 + qrow) * 2048 + hi * 8;
  s16x8 qf[4];
#pragma unroll
  for (int ki = 0; ki < 4; ++ki)
    qf[ki] = *(const s16x8*)&Q[(size_t)qrow * 64 + ki * 16 + hi * 8];
  s16x8 onesv;
#pragma unroll
  for (int i = 0; i < 8; ++i) onesv[i] = (short)0x3F80;   // bf16 1.0
  f32x16 oacc[2], lacc;
#pragma unroll
  for (int r = 0; r < 16; ++r) { oacc[0][r] = 0.f; oacc[1][r] = 0.f; lacc[r] = 0.f; }

  // prologue: stage tiles 0 and 1; wait only tile 0 (vmcnt leaves 4 of t=1)
  STAGE_KV(Kl[0], Vl[0], 0);
  STAGE_KV(Kl[1], Vl[1], 1);
  asm volatile("s_waitcnt vmcnt(4)" ::: "memory");
  __builtin_amdgcn_s_barrier();
  __builtin_amdgcn_sched_barrier(0);

  int cur = 0;
#pragma unroll 1
  for (int kt = 0; kt < 32; ++kt) {
    s16x8 bv_[4];
    LOAD_B(bv_, kt);                      // bias first (drained pre-barrier)
    int nb = cur + 2; if (nb >= 3) nb -= 3;
    if (kt + 2 < 32) STAGE_KV(Kl[nb], Vl[nb], kt + 2);
    COMPUTE_TILE(Kl[cur], Vl[cur], bv_);
    // keep the newest stage (kt+2, 4 loads) in flight across the barrier;
    // everything older (bias + stage kt+1) is provably drained.
    asm volatile("s_waitcnt vmcnt(4)" ::: "memory");
    __builtin_amdgcn_sched_barrier(0);
    __builtin_amdgcn_s_barrier();
    __builtin_amdgcn_sched_barrier(0);
    cur = cur + 1; if (cur >= 3) cur = 0;
  }
  float inv = 1.0f / lacc[0];
  size_t obase = ((size_t)b * 2048 + qrow) * 768 + h * 64;
#pragma unroll
  for (int dt = 0; dt < 2; ++dt) {
#pragma unroll
    for (int g = 0; g < 4; ++g) {
      s16x4 o4;
#pragma unroll
      for (int j = 0; j < 4; ++j)
        o4[j] = (short)f2bf(oacc[dt][g * 4 + j] * inv);
      *(s16x4*)&ctx[obase + dt * 32 + g * 8 + hi * 4] = o4;
    }
  }
}

// ---------------- Kernel 5: proj GEMM [8192,768] x [768,768] + b ---------
__global__ __launch_bounds__(256) void k_gemm_proj(
    const u16* __restrict__ A, const u16* __restrict__ Bt,
    const float* __restrict__ bias, float* __restrict__ out) {
  __shared__ u16 Al[128 * 64];
  __shared__ u16 Bl[128 * 64];
  int mt = blockIdx.x, nt = blockIdx.y;
  int t = threadIdx.x, wave = t >> 6, lane = t & 63;
  int lr = lane & 15, lg = lane >> 4;
  f32x4 acc[4][4];
#pragma unroll
  for (int i = 0; i < 4; ++i)
#pragma unroll
    for (int j = 0; j < 4; ++j) acc[i][j] = (f32x4){0.f, 0.f, 0.f, 0.f};
  const size_t Ab = (size_t)mt * 128 * 768;
  const size_t Bb = (size_t)nt * 128 * 768;
  int wr = (wave >> 1) * 64, wc = (wave & 1) * 64;
  for (int kt = 0; kt < 12; ++kt) {
#pragma unroll
    for (int c = 0; c < 4; ++c) {
      int q = c * 256 + t;
      int row = q >> 3, ch = q & 7;
      int sc = ch ^ (row & 7);
      GLD_LDS16(A + Ab + (size_t)row * 768 + kt * 64 + sc * 8,
                &Al[(size_t)(c * 256 + wave * 64) * 8]);
      GLD_LDS16(Bt + Bb + (size_t)row * 768 + kt * 64 + sc * 8,
                &Bl[(size_t)(c * 256 + wave * 64) * 8]);
    }
    __syncthreads();
#pragma unroll
    for (int ki = 0; ki < 2; ++ki) {
      s16x8 af[4], bf[4];
#pragma unroll
      for (int mi = 0; mi < 4; ++mi)
        af[mi] = *(const s16x8*)&Al[(wr + mi * 16 + lr) * 64 +
                                    (((ki * 4 + lg) ^ (lr & 7)) * 8)];
#pragma unroll
      for (int ni = 0; ni < 4; ++ni)
        bf[ni] = *(const s16x8*)&Bl[(wc + ni * 16 + lr) * 64 +
                                    (((ki * 4 + lg) ^ (lr & 7)) * 8)];
#pragma unroll
      for (int mi = 0; mi < 4; ++mi)
#pragma unroll
        for (int ni = 0; ni < 4; ++ni)
          acc[mi][ni] = __builtin_amdgcn_mfma_f32_16x16x32_bf16(
              af[mi], bf[ni], acc[mi][ni], 0, 0, 0);
    }
    __syncthreads();
  }
#pragma unroll
  for (int ni = 0; ni < 4; ++ni) {
    int col = wc + ni * 16 + lr;
    int n = nt * 128 + col;
    float bs = bias[n];
#pragma unroll
    for (int mi = 0; mi < 4; ++mi) {
#pragma unroll
      for (int j = 0; j < 4; ++j) {
        int row = wr + mi * 16 + lg * 4 + j;
        out[(size_t)(mt * 128 + row) * 768 + n] = acc[mi][ni][j] + bs;
      }
    }
  }
}

extern "C" void kernel_launch(void* const* d_in, const int* in_sizes, int n_in,
                              void* d_out, int out_size, void* d_ws, size_t ws_size,
                              hipStream_t stream) {
  const float* x      = (const float*)d_in[0];
  const float* pos    = (const float*)d_in[1];
  const float* bias   = (const float*)d_in[2];
  const float* ln_g   = (const float*)d_in[3];
  const float* ln_b   = (const float*)d_in[4];
  const float* qkv_w  = (const float*)d_in[5];
  const float* qkv_b  = (const float*)d_in[6];
  const float* proj_w = (const float*)d_in[7];
  const float* proj_b = (const float*)d_in[8];
  float* out = (float*)d_out;

  char* ws = (char*)d_ws;
  u16* xp      = (u16*)ws;              ws += 12582912;   // [8192][768]
  u16* qkv_wt  = (u16*)ws;              ws += 3538944;    // [2304][768]
  u16* proj_wt = (u16*)ws;              ws += 1179648;    // [768][768]
  u16* qkvbuf  = (u16*)ws;              ws += 25165824;   // Q,K [B,H,K,D]
  u16* ctx     = (u16*)ws;              ws += 12582912;   // [8192][768]
  u16* vtg     = (u16*)ws;              ws += 12582912;   // [B,H,D,K]
  u16* biasb   = (u16*)ws;              ws += 33554432;   // [4][2048][2048] bf16

  k_ln<<<8192, 256, 0, stream>>>(x, pos, ln_g, ln_b, xp);
  k_tr<<<dim3(72, 24), 256, 0, stream>>>(qkv_w, qkv_wt, 768, 2304);
  k_tr<<<dim3(24, 24), 256, 0, stream>>>(proj_w, proj_wt, 768, 768);
  k_gemm_qkv<<<dim3(64, 18), 256, 0, stream>>>(xp, qkv_wt, qkv_b, qkvbuf, vtg,
                                               bias, biasb);
  k_attn<<<768, 256, 0, stream>>>(qkvbuf, vtg, biasb, ctx);
  k_gemm_proj<<<dim3(64, 6), 256, 0, stream>>>(ctx, proj_wt, proj_b, out);
}

// Round 19
// 181.337 us; speedup vs baseline: 1.4548x; 1.0117x over previous
//
#include <hip/hip_runtime.h>
#include <hip/hip_bf16.h>
#include <stdint.h>

typedef __attribute__((ext_vector_type(4))) float f32x4;
typedef __attribute__((ext_vector_type(16))) float f32x16;
typedef __attribute__((ext_vector_type(8))) short s16x8;
typedef __attribute__((ext_vector_type(4))) short s16x4;
typedef uint16_t u16;

#define DEV __device__ __forceinline__

static DEV u16 f2bf(float f) {
  union { float f; uint32_t u; } v; v.f = f;
  uint32_t r = v.u + 0x7fffu + ((v.u >> 16) & 1u);
  return (u16)(r >> 16);
}

static DEV float bf2f(u16 x) {
  union { uint32_t u; float f; } v; v.u = ((uint32_t)x) << 16;
  return v.f;
}

static DEV uint32_t cvt_pk_bf16(float lo, float hi) {
  uint32_t r;
  asm("v_cvt_pk_bf16_f32 %0, %1, %2" : "=v"(r) : "v"(lo), "v"(hi));
  return r;
}

// bare 2^x via the compiler-visible intrinsic (hazard-safe; R17's opaque
// inline asm hid the TRANS read hazard -> corruption; R18 fixed + -23 us).
#if defined(__has_builtin) && __has_builtin(__builtin_amdgcn_exp2f)
static DEV float exp2_fast(float x) { return __builtin_amdgcn_exp2f(x); }
#else
static DEV float exp2_fast(float x) {
  float r;
  asm("v_exp_f32 %0, %1\n\ts_nop 1" : "=v"(r) : "v"(x));
  return r;
}
#endif

#define GLD_LDS16(gp, lp) __builtin_amdgcn_global_load_lds( \
    (const __attribute__((address_space(1))) void*)(gp),    \
    (__attribute__((address_space(3))) void*)(lp), 16, 0, 0)

// ---------------- Kernel 1: LayerNorm + pos_embed -> bf16 ----------------
__global__ __launch_bounds__(256) void k_ln(
    const float* __restrict__ x, const float* __restrict__ pos,
    const float* __restrict__ g, const float* __restrict__ be,
    u16* __restrict__ xp) {
  int row = blockIdx.x;
  size_t base = (size_t)row * 768;
  int t = threadIdx.x;
  float v0 = x[base + t], v1 = x[base + t + 256], v2 = x[base + t + 512];
  float s = v0 + v1 + v2;
  float ss = v0 * v0 + v1 * v1 + v2 * v2;
#pragma unroll
  for (int off = 1; off < 64; off <<= 1) {
    s += __shfl_xor(s, off);
    ss += __shfl_xor(ss, off);
  }
  __shared__ float red[8];
  int wave = t >> 6, lane = t & 63;
  if (lane == 0) { red[wave] = s; red[4 + wave] = ss; }
  __syncthreads();
  float tot = red[0] + red[1] + red[2] + red[3];
  float tss = red[4] + red[5] + red[6] + red[7];
  float mu = tot * (1.0f / 768.0f);
  float var = tss * (1.0f / 768.0f) - mu * mu;
  float rs = rsqrtf(var + 1e-5f);
  float vv[3] = {v0, v1, v2};
#pragma unroll
  for (int i = 0; i < 3; ++i) {
    int c = t + i * 256;
    float val = (vv[i] - mu) * rs * g[c] + be[c] + pos[base + c];
    xp[base + c] = f2bf(val);
  }
}

// ---------------- Kernel 2: transpose + cast f32[K][N] -> bf16[N][K] -----
__global__ __launch_bounds__(256) void k_tr(
    const float* __restrict__ in, u16* __restrict__ out, int K, int N) {
  __shared__ float tile[32][33];
  int n0 = blockIdx.x * 32, k0 = blockIdx.y * 32;
  int tx = threadIdx.x & 31, ty = threadIdx.x >> 5;
#pragma unroll
  for (int r = ty; r < 32; r += 8)
    tile[r][tx] = in[(size_t)(k0 + r) * N + n0 + tx];
  __syncthreads();
#pragma unroll
  for (int r = ty; r < 32; r += 8)
    out[(size_t)(n0 + r) * K + k0 + tx] = f2bf(tile[tx][r]);
}

// ---------------- Kernel 3: QKV GEMM + fused bias cast -------------------
__global__ __launch_bounds__(256) void k_gemm_qkv(
    const u16* __restrict__ A, const u16* __restrict__ Bt,
    const float* __restrict__ bias, u16* __restrict__ qkv,
    u16* __restrict__ vtg, const float* __restrict__ biasf,
    u16* __restrict__ biasb) {
  __shared__ u16 Al[128 * 64];
  __shared__ u16 Bl[128 * 64];
  const size_t BHKD = (size_t)48 * 2048 * 64;
  int mt = blockIdx.x, nt = blockIdx.y;
  int t = threadIdx.x, wave = t >> 6, lane = t & 63;
  int lr = lane & 15, lg = lane >> 4;
  // ---- fused bias cast (biasb consumed by k_attn) ----
  {
    size_t tid = ((size_t)(nt * 64 + mt) * 256 + t) * 8;
    size_t stride = (size_t)1152 * 256 * 8;
    const size_t NB = (size_t)4 * 2048 * 2048;
    for (size_t i = tid; i < NB; i += stride) {
      f32x4 a = *(const f32x4*)(biasf + i);
      f32x4 b = *(const f32x4*)(biasf + i + 4);
      s16x8 o;
#pragma unroll
      for (int j = 0; j < 4; ++j) o[j] = (short)f2bf(a[j] * 1.4426950409f);
#pragma unroll
      for (int j = 0; j < 4; ++j) o[4 + j] = (short)f2bf(b[j] * 1.4426950409f);
      *(s16x8*)(biasb + i) = o;
    }
  }
  f32x4 acc[4][4];
#pragma unroll
  for (int i = 0; i < 4; ++i)
#pragma unroll
    for (int j = 0; j < 4; ++j) acc[i][j] = (f32x4){0.f, 0.f, 0.f, 0.f};
  const size_t Ab = (size_t)mt * 128 * 768;
  const size_t Bb = (size_t)nt * 128 * 768;
  int wr = (wave >> 1) * 64, wc = (wave & 1) * 64;
  for (int kt = 0; kt < 12; ++kt) {
#pragma unroll
    for (int c = 0; c < 4; ++c) {
      int q = c * 256 + t;
      int row = q >> 3, ch = q & 7;
      int sc = ch ^ (row & 7);
      GLD_LDS16(A + Ab + (size_t)row * 768 + kt * 64 + sc * 8,
                &Al[(size_t)(c * 256 + wave * 64) * 8]);
      GLD_LDS16(Bt + Bb + (size_t)row * 768 + kt * 64 + sc * 8,
                &Bl[(size_t)(c * 256 + wave * 64) * 8]);
    }
    __syncthreads();
#pragma unroll
    for (int ki = 0; ki < 2; ++ki) {
      s16x8 af[4], bf[4];
#pragma unroll
      for (int mi = 0; mi < 4; ++mi)
        af[mi] = *(const s16x8*)&Al[(wr + mi * 16 + lr) * 64 +
                                    (((ki * 4 + lg) ^ (lr & 7)) * 8)];
#pragma unroll
      for (int ni = 0; ni < 4; ++ni)
        bf[ni] = *(const s16x8*)&Bl[(wc + ni * 16 + lr) * 64 +
                                    (((ki * 4 + lg) ^ (lr & 7)) * 8)];
#pragma unroll
      for (int mi = 0; mi < 4; ++mi)
#pragma unroll
        for (int ni = 0; ni < 4; ++ni)
          acc[mi][ni] = __builtin_amdgcn_mfma_f32_16x16x32_bf16(
              af[mi], bf[ni], acc[mi][ni], 0, 0, 0);
    }
    __syncthreads();
  }
  int which0 = (nt * 128) / 768;           // block-uniform (768 = 6*128)
  float qscale = (which0 == 0) ? 0.1803368801f : 1.0f;
#pragma unroll
  for (int ni = 0; ni < 4; ++ni) {
    int col = wc + ni * 16 + lr;
    int n = nt * 128 + col;
    int which = n / 768, cc = n % 768;
    int h = cc >> 6, d = cc & 63;
    float bs = bias[n];
    if (which == 2) {
#pragma unroll
      for (int mi = 0; mi < 4; ++mi) {
        int m0 = mt * 128 + wr + mi * 16 + lg * 4;
        int b = m0 >> 11, kp0 = m0 & 2047;
        s16x4 o4;
#pragma unroll
        for (int j = 0; j < 4; ++j) o4[j] = (short)f2bf(acc[mi][ni][j] + bs);
        *(s16x4*)&vtg[((size_t)(b * 12 + h) * 64 + d) * 2048 + kp0] = o4;
      }
    } else {
#pragma unroll
      for (int mi = 0; mi < 4; ++mi) {
#pragma unroll
        for (int j = 0; j < 4; ++j) {
          int row = wr + mi * 16 + lg * 4 + j;
          int m = mt * 128 + row;
          int b = m >> 11, kp = m & 2047;
          size_t dst = (size_t)which * BHKD +
                       (((size_t)b * 12 + h) * 2048 + kp) * 64 + d;
          qkv[dst] = f2bf((acc[mi][ni][j] + bs) * qscale);
        }
      }
    }
  }
}

// ---------------- Kernel 4: flash attention (no lacc chain) --------------
// R18 pipeline; l back on the VALU (31 independent adds overlap MFMA) --
// removes the 4-deep dependent lacc MFMA chain per tile (matrix pipe now
// issues only the mathematical minimum 16 MFMAs/tile).
#define STAGE_KV(KB, VB, ktt) do {                                          \
  _Pragma("unroll")                                                         \
  for (int c_ = 0; c_ < 2; ++c_) {                                          \
    int q_ = c_ * 256 + t; int r_ = q_ >> 3, ch_ = q_ & 7;                  \
    int sc_ = ch_ ^ (r_ & 7);                                               \
    int gk_ = (r_ & 0x33) | ((r_ & 4) << 1) | ((r_ & 8) >> 1);              \
    GLD_LDS16(Kg + ((size_t)((ktt) * 64 + gk_)) * 64 + sc_ * 8,             \
              &KB[(c_ * 256 + wave * 64) * 8]);                             \
    GLD_LDS16(Vt + (size_t)r_ * 2048 + (ktt) * 64 + sc_ * 8,                \
              &VB[(c_ * 256 + wave * 64) * 8]);                             \
  }                                                                         \
} while (0)

#define LOAD_B(BR, ktt) do {                                                \
  const u16* bp_ = Bgl + (ktt) * 64;                                        \
  BR[0] = *(const s16x8*)(bp_);                                             \
  BR[1] = *(const s16x8*)(bp_ + 16);                                        \
  BR[2] = *(const s16x8*)(bp_ + 32);                                        \
  BR[3] = *(const s16x8*)(bp_ + 48);                                        \
} while (0)

#define COMPUTE_TILE(KB, VB, BV) do {                                       \
  f32x16 sa_[2];                                                            \
  _Pragma("unroll")                                                         \
  for (int kv_ = 0; kv_ < 2; ++kv_)                                         \
    _Pragma("unroll")                                                       \
    for (int r = 0; r < 16; ++r)                                            \
      sa_[kv_][r] = bf2f((u16)BV[kv_ * 2 + (r >> 3)][r & 7]);               \
  __builtin_amdgcn_s_setprio(1);                                            \
  _Pragma("unroll")                                                         \
  for (int ki = 0; ki < 4; ++ki) {                                          \
    _Pragma("unroll")                                                       \
    for (int kv_ = 0; kv_ < 2; ++kv_) {                                     \
      s16x8 kf = *(const s16x8*)&KB[(kv_ * 32 + l31) * 64 +                 \
                                    (((ki * 2 + hi) ^ (l31 & 7)) * 8)];     \
      sa_[kv_] = __builtin_amdgcn_mfma_f32_32x32x16_bf16(kf, qf[ki],        \
                                                         sa_[kv_], 0, 0, 0);\
    }                                                                       \
  }                                                                         \
  __builtin_amdgcn_s_setprio(0);                                            \
  float p_[32];                                                             \
  _Pragma("unroll")                                                         \
  for (int kv_ = 0; kv_ < 2; ++kv_)                                         \
    _Pragma("unroll")                                                       \
    for (int r = 0; r < 16; ++r)                                            \
      p_[kv_ * 16 + r] = exp2_fast(sa_[kv_][r]);                            \
  float tm_[16];                                                            \
  _Pragma("unroll")                                                         \
  for (int i = 0; i < 16; ++i) tm_[i] = p_[i] + p_[i + 16];                 \
  _Pragma("unroll")                                                         \
  for (int off = 8; off >= 1; off >>= 1)                                    \
    _Pragma("unroll")                                                       \
    for (int i = 0; i < off; ++i) tm_[i] += tm_[i + off];                   \
  l_run += tm_[0];                                                          \
  union { uint32_t u[4]; s16x8 v; } pa_[4];                                 \
  _Pragma("unroll")                                                         \
  for (int s = 0; s < 4; ++s)                                               \
    _Pragma("unroll")                                                       \
    for (int w = 0; w < 4; ++w)                                             \
      pa_[s].u[w] = cvt_pk_bf16(p_[(s >> 1) * 16 + (s & 1) * 8 + 2 * w],    \
                                p_[(s >> 1) * 16 + (s & 1) * 8 + 2 * w + 1]);\
  __builtin_amdgcn_s_setprio(1);                                            \
  _Pragma("unroll")                                                         \
  for (int s = 0; s < 4; ++s) {                                             \
    _Pragma("unroll")                                                       \
    for (int dt = 0; dt < 2; ++dt) {                                        \
      s16x8 vf = *(const s16x8*)&VB[(dt * 32 + l31) * 64 +                  \
                                    (((s * 2 + hi) ^ (l31 & 7)) * 8)];      \
      oacc[dt] = __builtin_amdgcn_mfma_f32_32x32x16_bf16(vf, pa_[s].v,      \
                                                         oacc[dt], 0, 0, 0);\
    }                                                                       \
  }                                                                         \
  __builtin_amdgcn_s_setprio(0);                                            \
} while (0)

__global__ __launch_bounds__(256, 2) void k_attn(
    const u16* __restrict__ qkv, const u16* __restrict__ vtg,
    const u16* __restrict__ biasb, u16* __restrict__ ctx) {
  __shared__ u16 Kl[3][64 * 64];
  __shared__ u16 Vl[3][64 * 64];
  int bid = blockIdx.x;
  int swz = (bid & 7) * 96 + (bid >> 3);   // 768 = 8*96, bijective
  int h = swz % 12;
  int bq = swz / 12;        // 0..63
  int qt = bq & 15;
  int b = bq >> 4;
  int bh = b * 12 + h;
  int t = threadIdx.x, wave = t >> 6, lane = t & 63;
  int l31 = lane & 31, hi = lane >> 5;
  const size_t BHKD = (size_t)48 * 2048 * 64;
  const u16* Q = qkv + (size_t)bh * 2048 * 64;
  const u16* Kg = Q + BHKD;
  const u16* Vt = vtg + (size_t)bh * 64 * 2048;
  int qrow = qt * 128 + wave * 32 + l31;
  const u16* Bgl = biasb + ((size_t)b * 2048 + qrow) * 2048 + hi * 8;
  s16x8 qf[4];
#pragma unroll
  for (int ki = 0; ki < 4; ++ki)
    qf[ki] = *(const s16x8*)&Q[(size_t)qrow * 64 + ki * 16 + hi * 8];
  f32x16 oacc[2];
#pragma unroll
  for (int r = 0; r < 16; ++r) { oacc[0][r] = 0.f; oacc[1][r] = 0.f; }
  float l_run = 0.f;

  // prologue: stage tiles 0 and 1; wait only tile 0 (vmcnt leaves 4 of t=1)
  STAGE_KV(Kl[0], Vl[0], 0);
  STAGE_KV(Kl[1], Vl[1], 1);
  asm volatile("s_waitcnt vmcnt(4)" ::: "memory");
  __builtin_amdgcn_s_barrier();
  __builtin_amdgcn_sched_barrier(0);

  int cur = 0;
#pragma unroll 1
  for (int kt = 0; kt < 32; ++kt) {
    s16x8 bv_[4];
    LOAD_B(bv_, kt);                      // bias first (drained pre-barrier)
    int nb = cur + 2; if (nb >= 3) nb -= 3;
    if (kt + 2 < 32) STAGE_KV(Kl[nb], Vl[nb], kt + 2);
    COMPUTE_TILE(Kl[cur], Vl[cur], bv_);
    // keep the newest stage (kt+2, 4 loads) in flight across the barrier;
    // everything older (bias + stage kt+1) is provably drained.
    asm volatile("s_waitcnt vmcnt(4)" ::: "memory");
    __builtin_amdgcn_sched_barrier(0);
    __builtin_amdgcn_s_barrier();
    __builtin_amdgcn_sched_barrier(0);
    cur = cur + 1; if (cur >= 3) cur = 0;
  }
  float l_tot = l_run + __shfl_xor(l_run, 32);
  float inv = 1.0f / l_tot;
  size_t obase = ((size_t)b * 2048 + qrow) * 768 + h * 64;
#pragma unroll
  for (int dt = 0; dt < 2; ++dt) {
#pragma unroll
    for (int g = 0; g < 4; ++g) {
      s16x4 o4;
#pragma unroll
      for (int j = 0; j < 4; ++j)
        o4[j] = (short)f2bf(oacc[dt][g * 4 + j] * inv);
      *(s16x4*)&ctx[obase + dt * 32 + g * 8 + hi * 4] = o4;
    }
  }
}

// ---------------- Kernel 5: proj GEMM [8192,768] x [768,768] + b ---------
__global__ __launch_bounds__(256) void k_gemm_proj(
    const u16* __restrict__ A, const u16* __restrict__ Bt,
    const float* __restrict__ bias, float* __restrict__ out) {
  __shared__ u16 Al[128 * 64];
  __shared__ u16 Bl[128 * 64];
  int mt = blockIdx.x, nt = blockIdx.y;
  int t = threadIdx.x, wave = t >> 6, lane = t & 63;
  int lr = lane & 15, lg = lane >> 4;
  f32x4 acc[4][4];
#pragma unroll
  for (int i = 0; i < 4; ++i)
#pragma unroll
    for (int j = 0; j < 4; ++j) acc[i][j] = (f32x4){0.f, 0.f, 0.f, 0.f};
  const size_t Ab = (size_t)mt * 128 * 768;
  const size_t Bb = (size_t)nt * 128 * 768;
  int wr = (wave >> 1) * 64, wc = (wave & 1) * 64;
  for (int kt = 0; kt < 12; ++kt) {
#pragma unroll
    for (int c = 0; c < 4; ++c) {
      int q = c * 256 + t;
      int row = q >> 3, ch = q & 7;
      int sc = ch ^ (row & 7);
      GLD_LDS16(A + Ab + (size_t)row * 768 + kt * 64 + sc * 8,
                &Al[(size_t)(c * 256 + wave * 64) * 8]);
      GLD_LDS16(Bt + Bb + (size_t)row * 768 + kt * 64 + sc * 8,
                &Bl[(size_t)(c * 256 + wave * 64) * 8]);
    }
    __syncthreads();
#pragma unroll
    for (int ki = 0; ki < 2; ++ki) {
      s16x8 af[4], bf[4];
#pragma unroll
      for (int mi = 0; mi < 4; ++mi)
        af[mi] = *(const s16x8*)&Al[(wr + mi * 16 + lr) * 64 +
                                    (((ki * 4 + lg) ^ (lr & 7)) * 8)];
#pragma unroll
      for (int ni = 0; ni < 4; ++ni)
        bf[ni] = *(const s16x8*)&Bl[(wc + ni * 16 + lr) * 64 +
                                    (((ki * 4 + lg) ^ (lr & 7)) * 8)];
#pragma unroll
      for (int mi = 0; mi < 4; ++mi)
#pragma unroll
        for (int ni = 0; ni < 4; ++ni)
          acc[mi][ni] = __builtin_amdgcn_mfma_f32_16x16x32_bf16(
              af[mi], bf[ni], acc[mi][ni], 0, 0, 0);
    }
    __syncthreads();
  }
#pragma unroll
  for (int ni = 0; ni < 4; ++ni) {
    int col = wc + ni * 16 + lr;
    int n = nt * 128 + col;
    float bs = bias[n];
#pragma unroll
    for (int mi = 0; mi < 4; ++mi) {
#pragma unroll
      for (int j = 0; j < 4; ++j) {
        int row = wr + mi * 16 + lg * 4 + j;
        out[(size_t)(mt * 128 + row) * 768 + n] = acc[mi][ni][j] + bs;
      }
    }
  }
}

extern "C" void kernel_launch(void* const* d_in, const int* in_sizes, int n_in,
                              void* d_out, int out_size, void* d_ws, size_t ws_size,
                              hipStream_t stream) {
  const float* x      = (const float*)d_in[0];
  const float* pos    = (const float*)d_in[1];
  const float* bias   = (const float*)d_in[2];
  const float* ln_g   = (const float*)d_in[3];
  const float* ln_b   = (const float*)d_in[4];
  const float* qkv_w  = (const float*)d_in[5];
  const float* qkv_b  = (const float*)d_in[6];
  const float* proj_w = (const float*)d_in[7];
  const float* proj_b = (const float*)d_in[8];
  float* out = (float*)d_out;

  char* ws = (char*)d_ws;
  u16* xp      = (u16*)ws;              ws += 12582912;   // [8192][768]
  u16* qkv_wt  = (u16*)ws;              ws += 3538944;    // [2304][768]
  u16* proj_wt = (u16*)ws;              ws += 1179648;    // [768][768]
  u16* qkvbuf  = (u16*)ws;              ws += 25165824;   // Q,K [B,H,K,D]
  u16* ctx     = (u16*)ws;              ws += 12582912;   // [8192][768]
  u16* vtg     = (u16*)ws;              ws += 12582912;   // [B,H,D,K]
  u16* biasb   = (u16*)ws;              ws += 33554432;   // [4][2048][2048] bf16

  k_ln<<<8192, 256, 0, stream>>>(x, pos, ln_g, ln_b, xp);
  k_tr<<<dim3(72, 24), 256, 0, stream>>>(qkv_w, qkv_wt, 768, 2304);
  k_tr<<<dim3(24, 24), 256, 0, stream>>>(proj_w, proj_wt, 768, 768);
  k_gemm_qkv<<<dim3(64, 18), 256, 0, stream>>>(xp, qkv_wt, qkv_b, qkvbuf, vtg,
                                               bias, biasb);
  k_attn<<<768, 256, 0, stream>>>(qkvbuf, vtg, biasb, ctx);
  k_gemm_proj<<<dim3(64, 6), 256, 0, stream>>>(ctx, proj_wt, proj_b, out);
}

// Round 20
// 176.092 us; speedup vs baseline: 1.4981x; 1.0298x over previous
//
#include <hip/hip_runtime.h>
#include <hip/hip_bf16.h>
#include <stdint.h>

typedef __attribute__((ext_vector_type(4))) float f32x4;
typedef __attribute__((ext_vector_type(16))) float f32x16;
typedef __attribute__((ext_vector_type(8))) short s16x8;
typedef __attribute__((ext_vector_type(4))) short s16x4;
typedef uint16_t u16;

#define DEV __device__ __forceinline__

static DEV u16 f2bf(float f) {
  union { float f; uint32_t u; } v; v.f = f;
  uint32_t r = v.u + 0x7fffu + ((v.u >> 16) & 1u);
  return (u16)(r >> 16);
}

static DEV float bf2f(u16 x) {
  union { uint32_t u; float f; } v; v.u = ((uint32_t)x) << 16;
  return v.f;
}

static DEV uint32_t cvt_pk_bf16(float lo, float hi) {
  uint32_t r;
  asm("v_cvt_pk_bf16_f32 %0, %1, %2" : "=v"(r) : "v"(lo), "v"(hi));
  return r;
}

// bare 2^x via the compiler-visible intrinsic (hazard-safe; R17's opaque
// inline asm hid the TRANS read hazard -> corruption; R18 fixed + -23 us).
#if defined(__has_builtin) && __has_builtin(__builtin_amdgcn_exp2f)
static DEV float exp2_fast(float x) { return __builtin_amdgcn_exp2f(x); }
#else
static DEV float exp2_fast(float x) {
  float r;
  asm("v_exp_f32 %0, %1\n\ts_nop 1" : "=v"(r) : "v"(x));
  return r;
}
#endif

#define GLD_LDS16(gp, lp) __builtin_amdgcn_global_load_lds( \
    (const __attribute__((address_space(1))) void*)(gp),    \
    (__attribute__((address_space(3))) void*)(lp), 16, 0, 0)

// ---------------- Kernel 1: LayerNorm + pos_embed -> bf16 ----------------
__global__ __launch_bounds__(256) void k_ln(
    const float* __restrict__ x, const float* __restrict__ pos,
    const float* __restrict__ g, const float* __restrict__ be,
    u16* __restrict__ xp) {
  int row = blockIdx.x;
  size_t base = (size_t)row * 768;
  int t = threadIdx.x;
  float v0 = x[base + t], v1 = x[base + t + 256], v2 = x[base + t + 512];
  float s = v0 + v1 + v2;
  float ss = v0 * v0 + v1 * v1 + v2 * v2;
#pragma unroll
  for (int off = 1; off < 64; off <<= 1) {
    s += __shfl_xor(s, off);
    ss += __shfl_xor(ss, off);
  }
  __shared__ float red[8];
  int wave = t >> 6, lane = t & 63;
  if (lane == 0) { red[wave] = s; red[4 + wave] = ss; }
  __syncthreads();
  float tot = red[0] + red[1] + red[2] + red[3];
  float tss = red[4] + red[5] + red[6] + red[7];
  float mu = tot * (1.0f / 768.0f);
  float var = tss * (1.0f / 768.0f) - mu * mu;
  float rs = rsqrtf(var + 1e-5f);
  float vv[3] = {v0, v1, v2};
#pragma unroll
  for (int i = 0; i < 3; ++i) {
    int c = t + i * 256;
    float val = (vv[i] - mu) * rs * g[c] + be[c] + pos[base + c];
    xp[base + c] = f2bf(val);
  }
}

// ---------------- Kernel 2: transpose + cast f32[K][N] -> bf16[N][K] -----
__global__ __launch_bounds__(256) void k_tr(
    const float* __restrict__ in, u16* __restrict__ out, int K, int N) {
  __shared__ float tile[32][33];
  int n0 = blockIdx.x * 32, k0 = blockIdx.y * 32;
  int tx = threadIdx.x & 31, ty = threadIdx.x >> 5;
#pragma unroll
  for (int r = ty; r < 32; r += 8)
    tile[r][tx] = in[(size_t)(k0 + r) * N + n0 + tx];
  __syncthreads();
#pragma unroll
  for (int r = ty; r < 32; r += 8)
    out[(size_t)(n0 + r) * K + k0 + tx] = f2bf(tile[tx][r]);
}

// ---------------- Kernel 3: QKV GEMM + interleaved bias cast -------------
// Bias cast (f32 -> bf16*log2e) interleaved INTO the K-loop: one coalesced
// grid-stride chunk per kt (kt<8); its loads queue behind the staging loads
// and complete under the MFMA phase, so the cast rides the GEMM's existing
// latency shadow instead of serializing as a prologue (R16: ~18 us serial).
__global__ __launch_bounds__(256) void k_gemm_qkv(
    const u16* __restrict__ A, const u16* __restrict__ Bt,
    const float* __restrict__ bias, u16* __restrict__ qkv,
    u16* __restrict__ vtg, const float* __restrict__ biasf,
    u16* __restrict__ biasb) {
  __shared__ u16 Al[128 * 64];
  __shared__ u16 Bl[128 * 64];
  const size_t BHKD = (size_t)48 * 2048 * 64;
  const size_t NB = (size_t)4 * 2048 * 2048;
  int mt = blockIdx.x, nt = blockIdx.y;
  int t = threadIdx.x, wave = t >> 6, lane = t & 63;
  int lr = lane & 15, lg = lane >> 4;
  f32x4 acc[4][4];
#pragma unroll
  for (int i = 0; i < 4; ++i)
#pragma unroll
    for (int j = 0; j < 4; ++j) acc[i][j] = (f32x4){0.f, 0.f, 0.f, 0.f};
  const size_t Ab = (size_t)mt * 128 * 768;
  const size_t Bb = (size_t)nt * 128 * 768;
  int wr = (wave >> 1) * 64, wc = (wave & 1) * 64;
  for (int kt = 0; kt < 12; ++kt) {
#pragma unroll
    for (int c = 0; c < 4; ++c) {
      int q = c * 256 + t;
      int row = q >> 3, ch = q & 7;
      int sc = ch ^ (row & 7);
      GLD_LDS16(A + Ab + (size_t)row * 768 + kt * 64 + sc * 8,
                &Al[(size_t)(c * 256 + wave * 64) * 8]);
      GLD_LDS16(Bt + Bb + (size_t)row * 768 + kt * 64 + sc * 8,
                &Bl[(size_t)(c * 256 + wave * 64) * 8]);
    }
    // interleaved bias-cast chunk (iteration-major -> coalesced)
    if (kt < 8) {
      size_t i = ((size_t)kt * 1152 * 256 +
                  (size_t)(nt * 64 + mt) * 256 + t) * 8;
      if (i < NB) {
        f32x4 a = *(const f32x4*)(biasf + i);
        f32x4 b = *(const f32x4*)(biasf + i + 4);
        s16x8 o;
#pragma unroll
        for (int j = 0; j < 4; ++j) o[j] = (short)f2bf(a[j] * 1.4426950409f);
#pragma unroll
        for (int j = 0; j < 4; ++j) o[4 + j] = (short)f2bf(b[j] * 1.4426950409f);
        *(s16x8*)(biasb + i) = o;
      }
    }
    __syncthreads();
#pragma unroll
    for (int ki = 0; ki < 2; ++ki) {
      s16x8 af[4], bf[4];
#pragma unroll
      for (int mi = 0; mi < 4; ++mi)
        af[mi] = *(const s16x8*)&Al[(wr + mi * 16 + lr) * 64 +
                                    (((ki * 4 + lg) ^ (lr & 7)) * 8)];
#pragma unroll
      for (int ni = 0; ni < 4; ++ni)
        bf[ni] = *(const s16x8*)&Bl[(wc + ni * 16 + lr) * 64 +
                                    (((ki * 4 + lg) ^ (lr & 7)) * 8)];
#pragma unroll
      for (int mi = 0; mi < 4; ++mi)
#pragma unroll
        for (int ni = 0; ni < 4; ++ni)
          acc[mi][ni] = __builtin_amdgcn_mfma_f32_16x16x32_bf16(
              af[mi], bf[ni], acc[mi][ni], 0, 0, 0);
    }
    __syncthreads();
  }
  int which0 = (nt * 128) / 768;           // block-uniform (768 = 6*128)
  float qscale = (which0 == 0) ? 0.1803368801f : 1.0f;
#pragma unroll
  for (int ni = 0; ni < 4; ++ni) {
    int col = wc + ni * 16 + lr;
    int n = nt * 128 + col;
    int which = n / 768, cc = n % 768;
    int h = cc >> 6, d = cc & 63;
    float bs = bias[n];
    if (which == 2) {
#pragma unroll
      for (int mi = 0; mi < 4; ++mi) {
        int m0 = mt * 128 + wr + mi * 16 + lg * 4;
        int b = m0 >> 11, kp0 = m0 & 2047;
        s16x4 o4;
#pragma unroll
        for (int j = 0; j < 4; ++j) o4[j] = (short)f2bf(acc[mi][ni][j] + bs);
        *(s16x4*)&vtg[((size_t)(b * 12 + h) * 64 + d) * 2048 + kp0] = o4;
      }
    } else {
#pragma unroll
      for (int mi = 0; mi < 4; ++mi) {
#pragma unroll
        for (int j = 0; j < 4; ++j) {
          int row = wr + mi * 16 + lg * 4 + j;
          int m = mt * 128 + row;
          int b = m >> 11, kp = m & 2047;
          size_t dst = (size_t)which * BHKD +
                       (((size_t)b * 12 + h) * 2048 + kp) * 64 + d;
          qkv[dst] = f2bf((acc[mi][ni][j] + bs) * qscale);
        }
      }
    }
  }
}

// ---------------- Kernel 4: flash attention (R19 best) -------------------
#define STAGE_KV(KB, VB, ktt) do {                                          \
  _Pragma("unroll")                                                         \
  for (int c_ = 0; c_ < 2; ++c_) {                                          \
    int q_ = c_ * 256 + t; int r_ = q_ >> 3, ch_ = q_ & 7;                  \
    int sc_ = ch_ ^ (r_ & 7);                                               \
    int gk_ = (r_ & 0x33) | ((r_ & 4) << 1) | ((r_ & 8) >> 1);              \
    GLD_LDS16(Kg + ((size_t)((ktt) * 64 + gk_)) * 64 + sc_ * 8,             \
              &KB[(c_ * 256 + wave * 64) * 8]);                             \
    GLD_LDS16(Vt + (size_t)r_ * 2048 + (ktt) * 64 + sc_ * 8,                \
              &VB[(c_ * 256 + wave * 64) * 8]);                             \
  }                                                                         \
} while (0)

#define LOAD_B(BR, ktt) do {                                                \
  const u16* bp_ = Bgl + (ktt) * 64;                                        \
  BR[0] = *(const s16x8*)(bp_);                                             \
  BR[1] = *(const s16x8*)(bp_ + 16);                                        \
  BR[2] = *(const s16x8*)(bp_ + 32);                                        \
  BR[3] = *(const s16x8*)(bp_ + 48);                                        \
} while (0)

#define COMPUTE_TILE(KB, VB, BV) do {                                       \
  f32x16 sa_[2];                                                            \
  _Pragma("unroll")                                                         \
  for (int kv_ = 0; kv_ < 2; ++kv_)                                         \
    _Pragma("unroll")                                                       \
    for (int r = 0; r < 16; ++r)                                            \
      sa_[kv_][r] = bf2f((u16)BV[kv_ * 2 + (r >> 3)][r & 7]);               \
  __builtin_amdgcn_s_setprio(1);                                            \
  _Pragma("unroll")                                                         \
  for (int ki = 0; ki < 4; ++ki) {                                          \
    _Pragma("unroll")                                                       \
    for (int kv_ = 0; kv_ < 2; ++kv_) {                                     \
      s16x8 kf = *(const s16x8*)&KB[(kv_ * 32 + l31) * 64 +                 \
                                    (((ki * 2 + hi) ^ (l31 & 7)) * 8)];     \
      sa_[kv_] = __builtin_amdgcn_mfma_f32_32x32x16_bf16(kf, qf[ki],        \
                                                         sa_[kv_], 0, 0, 0);\
    }                                                                       \
  }                                                                         \
  __builtin_amdgcn_s_setprio(0);                                            \
  float p_[32];                                                             \
  _Pragma("unroll")                                                         \
  for (int kv_ = 0; kv_ < 2; ++kv_)                                         \
    _Pragma("unroll")                                                       \
    for (int r = 0; r < 16; ++r)                                            \
      p_[kv_ * 16 + r] = exp2_fast(sa_[kv_][r]);                            \
  float tm_[16];                                                            \
  _Pragma("unroll")                                                         \
  for (int i = 0; i < 16; ++i) tm_[i] = p_[i] + p_[i + 16];                 \
  _Pragma("unroll")                                                         \
  for (int off = 8; off >= 1; off >>= 1)                                    \
    _Pragma("unroll")                                                       \
    for (int i = 0; i < off; ++i) tm_[i] += tm_[i + off];                   \
  l_run += tm_[0];                                                          \
  union { uint32_t u[4]; s16x8 v; } pa_[4];                                 \
  _Pragma("unroll")                                                         \
  for (int s = 0; s < 4; ++s)                                               \
    _Pragma("unroll")                                                       \
    for (int w = 0; w < 4; ++w)                                             \
      pa_[s].u[w] = cvt_pk_bf16(p_[(s >> 1) * 16 + (s & 1) * 8 + 2 * w],    \
                                p_[(s >> 1) * 16 + (s & 1) * 8 + 2 * w + 1]);\
  __builtin_amdgcn_s_setprio(1);                                            \
  _Pragma("unroll")                                                         \
  for (int s = 0; s < 4; ++s) {                                             \
    _Pragma("unroll")                                                       \
    for (int dt = 0; dt < 2; ++dt) {                                        \
      s16x8 vf = *(const s16x8*)&VB[(dt * 32 + l31) * 64 +                  \
                                    (((s * 2 + hi) ^ (l31 & 7)) * 8)];      \
      oacc[dt] = __builtin_amdgcn_mfma_f32_32x32x16_bf16(vf, pa_[s].v,      \
                                                         oacc[dt], 0, 0, 0);\
    }                                                                       \
  }                                                                         \
  __builtin_amdgcn_s_setprio(0);                                            \
} while (0)

__global__ __launch_bounds__(256, 2) void k_attn(
    const u16* __restrict__ qkv, const u16* __restrict__ vtg,
    const u16* __restrict__ biasb, u16* __restrict__ ctx) {
  __shared__ u16 Kl[3][64 * 64];
  __shared__ u16 Vl[3][64 * 64];
  int bid = blockIdx.x;
  int swz = (bid & 7) * 96 + (bid >> 3);   // 768 = 8*96, bijective
  int h = swz % 12;
  int bq = swz / 12;        // 0..63
  int qt = bq & 15;
  int b = bq >> 4;
  int bh = b * 12 + h;
  int t = threadIdx.x, wave = t >> 6, lane = t & 63;
  int l31 = lane & 31, hi = lane >> 5;
  const size_t BHKD = (size_t)48 * 2048 * 64;
  const u16* Q = qkv + (size_t)bh * 2048 * 64;
  const u16* Kg = Q + BHKD;
  const u16* Vt = vtg + (size_t)bh * 64 * 2048;
  int qrow = qt * 128 + wave * 32 + l31;
  const u16* Bgl = biasb + ((size_t)b * 2048 + qrow) * 2048 + hi * 8;
  s16x8 qf[4];
#pragma unroll
  for (int ki = 0; ki < 4; ++ki)
    qf[ki] = *(const s16x8*)&Q[(size_t)qrow * 64 + ki * 16 + hi * 8];
  f32x16 oacc[2];
#pragma unroll
  for (int r = 0; r < 16; ++r) { oacc[0][r] = 0.f; oacc[1][r] = 0.f; }
  float l_run = 0.f;

  // prologue: stage tiles 0 and 1; wait only tile 0 (vmcnt leaves 4 of t=1)
  STAGE_KV(Kl[0], Vl[0], 0);
  STAGE_KV(Kl[1], Vl[1], 1);
  asm volatile("s_waitcnt vmcnt(4)" ::: "memory");
  __builtin_amdgcn_s_barrier();
  __builtin_amdgcn_sched_barrier(0);

  int cur = 0;
#pragma unroll 1
  for (int kt = 0; kt < 32; ++kt) {
    s16x8 bv_[4];
    LOAD_B(bv_, kt);                      // bias first (drained pre-barrier)
    int nb = cur + 2; if (nb >= 3) nb -= 3;
    if (kt + 2 < 32) STAGE_KV(Kl[nb], Vl[nb], kt + 2);
    COMPUTE_TILE(Kl[cur], Vl[cur], bv_);
    // keep the newest stage (kt+2, 4 loads) in flight across the barrier;
    // everything older (bias + stage kt+1) is provably drained.
    asm volatile("s_waitcnt vmcnt(4)" ::: "memory");
    __builtin_amdgcn_sched_barrier(0);
    __builtin_amdgcn_s_barrier();
    __builtin_amdgcn_sched_barrier(0);
    cur = cur + 1; if (cur >= 3) cur = 0;
  }
  float l_tot = l_run + __shfl_xor(l_run, 32);
  float inv = 1.0f / l_tot;
  size_t obase = ((size_t)b * 2048 + qrow) * 768 + h * 64;
#pragma unroll
  for (int dt = 0; dt < 2; ++dt) {
#pragma unroll
    for (int g = 0; g < 4; ++g) {
      s16x4 o4;
#pragma unroll
      for (int j = 0; j < 4; ++j)
        o4[j] = (short)f2bf(oacc[dt][g * 4 + j] * inv);
      *(s16x4*)&ctx[obase + dt * 32 + g * 8 + hi * 4] = o4;
    }
  }
}

// ---------------- Kernel 5: proj GEMM [8192,768] x [768,768] + b ---------
__global__ __launch_bounds__(256) void k_gemm_proj(
    const u16* __restrict__ A, const u16* __restrict__ Bt,
    const float* __restrict__ bias, float* __restrict__ out) {
  __shared__ u16 Al[128 * 64];
  __shared__ u16 Bl[128 * 64];
  int mt = blockIdx.x, nt = blockIdx.y;
  int t = threadIdx.x, wave = t >> 6, lane = t & 63;
  int lr = lane & 15, lg = lane >> 4;
  f32x4 acc[4][4];
#pragma unroll
  for (int i = 0; i < 4; ++i)
#pragma unroll
    for (int j = 0; j < 4; ++j) acc[i][j] = (f32x4){0.f, 0.f, 0.f, 0.f};
  const size_t Ab = (size_t)mt * 128 * 768;
  const size_t Bb = (size_t)nt * 128 * 768;
  int wr = (wave >> 1) * 64, wc = (wave & 1) * 64;
  for (int kt = 0; kt < 12; ++kt) {
#pragma unroll
    for (int c = 0; c < 4; ++c) {
      int q = c * 256 + t;
      int row = q >> 3, ch = q & 7;
      int sc = ch ^ (row & 7);
      GLD_LDS16(A + Ab + (size_t)row * 768 + kt * 64 + sc * 8,
                &Al[(size_t)(c * 256 + wave * 64) * 8]);
      GLD_LDS16(Bt + Bb + (size_t)row * 768 + kt * 64 + sc * 8,
                &Bl[(size_t)(c * 256 + wave * 64) * 8]);
    }
    __syncthreads();
#pragma unroll
    for (int ki = 0; ki < 2; ++ki) {
      s16x8 af[4], bf[4];
#pragma unroll
      for (int mi = 0; mi < 4; ++mi)
        af[mi] = *(const s16x8*)&Al[(wr + mi * 16 + lr) * 64 +
                                    (((ki * 4 + lg) ^ (lr & 7)) * 8)];
#pragma unroll
      for (int ni = 0; ni < 4; ++ni)
        bf[ni] = *(const s16x8*)&Bl[(wc + ni * 16 + lr) * 64 +
                                    (((ki * 4 + lg) ^ (lr & 7)) * 8)];
#pragma unroll
      for (int mi = 0; mi < 4; ++mi)
#pragma unroll
        for (int ni = 0; ni < 4; ++ni)
          acc[mi][ni] = __builtin_amdgcn_mfma_f32_16x16x32_bf16(
              af[mi], bf[ni], acc[mi][ni], 0, 0, 0);
    }
    __syncthreads();
  }
#pragma unroll
  for (int ni = 0; ni < 4; ++ni) {
    int col = wc + ni * 16 + lr;
    int n = nt * 128 + col;
    float bs = bias[n];
#pragma unroll
    for (int mi = 0; mi < 4; ++mi) {
#pragma unroll
      for (int j = 0; j < 4; ++j) {
        int row = wr + mi * 16 + lg * 4 + j;
        out[(size_t)(mt * 128 + row) * 768 + n] = acc[mi][ni][j] + bs;
      }
    }
  }
}

extern "C" void kernel_launch(void* const* d_in, const int* in_sizes, int n_in,
                              void* d_out, int out_size, void* d_ws, size_t ws_size,
                              hipStream_t stream) {
  const float* x      = (const float*)d_in[0];
  const float* pos    = (const float*)d_in[1];
  const float* bias   = (const float*)d_in[2];
  const float* ln_g   = (const float*)d_in[3];
  const float* ln_b   = (const float*)d_in[4];
  const float* qkv_w  = (const float*)d_in[5];
  const float* qkv_b  = (const float*)d_in[6];
  const float* proj_w = (const float*)d_in[7];
  const float* proj_b = (const float*)d_in[8];
  float* out = (float*)d_out;

  char* ws = (char*)d_ws;
  u16* xp      = (u16*)ws;              ws += 12582912;   // [8192][768]
  u16* qkv_wt  = (u16*)ws;              ws += 3538944;    // [2304][768]
  u16* proj_wt = (u16*)ws;              ws += 1179648;    // [768][768]
  u16* qkvbuf  = (u16*)ws;              ws += 25165824;   // Q,K [B,H,K,D]
  u16* ctx     = (u16*)ws;              ws += 12582912;   // [8192][768]
  u16* vtg     = (u16*)ws;              ws += 12582912;   // [B,H,D,K]
  u16* biasb   = (u16*)ws;              ws += 33554432;   // [4][2048][2048] bf16

  k_ln<<<8192, 256, 0, stream>>>(x, pos, ln_g, ln_b, xp);
  k_tr<<<dim3(72, 24), 256, 0, stream>>>(qkv_w, qkv_wt, 768, 2304);
  k_tr<<<dim3(24, 24), 256, 0, stream>>>(proj_w, proj_wt, 768, 768);
  k_gemm_qkv<<<dim3(64, 18), 256, 0, stream>>>(xp, qkv_wt, qkv_b, qkvbuf, vtg,
                                               bias, biasb);
  k_attn<<<768, 256, 0, stream>>>(qkvbuf, vtg, biasb, ctx);
  k_gemm_proj<<<dim3(64, 6), 256, 0, stream>>>(ctx, proj_wt, proj_b, out);
}